// Round 6
// baseline (721.266 us; speedup 1.0000x reference)
//
#include <hip/hip_runtime.h>
#include <math.h>
#include <stdint.h>

#define B_BATCH 4
#define T_SEQ   2048
#define C_EMB   1024
#define NH      16
#define HS      64

typedef _Float16 half_t;
typedef __attribute__((ext_vector_type(8))) _Float16 half8;   // 4 VGPRs, 16 B
typedef __attribute__((ext_vector_type(4))) _Float16 half4;   // 2 VGPRs, 8 B
typedef __attribute__((ext_vector_type(2))) __fp16 pk16x2;    // cvt_pkrtz result type
typedef __attribute__((ext_vector_type(4))) float f32x4;

// K=16 f16 MFMA; fallback = zero-padded K=32 (A/B agree on slot map -> same dot)
static __device__ __forceinline__ f32x4 mfma_k16(half4 a, half4 b, f32x4 c) {
#if __has_builtin(__builtin_amdgcn_mfma_f32_16x16x16f16)
    return __builtin_amdgcn_mfma_f32_16x16x16f16(a, b, c, 0, 0, 0);
#else
    half8 a8 = {a.x, a.y, a.z, a.w, (_Float16)0, (_Float16)0, (_Float16)0, (_Float16)0};
    half8 b8 = {b.x, b.y, b.z, b.w, (_Float16)0, (_Float16)0, (_Float16)0, (_Float16)0};
    return __builtin_amdgcn_mfma_f32_16x16x32_f16(a8, b8, c, 0, 0, 0);
#endif
}

// async global->LDS, 16B/lane; LDS dest = wave-uniform base + lane*16
static __device__ __forceinline__ void stage16(const void* g, void* lds_base) {
#if __has_builtin(__builtin_amdgcn_global_load_lds)
    __builtin_amdgcn_global_load_lds(
        (const __attribute__((address_space(1))) void*)g,
        (__attribute__((address_space(3))) void*)lds_base, 16, 0, 0);
#else
    const int lane = threadIdx.x & 63;
    ((uint4*)lds_base)[lane] = *(const uint4*)g;
#endif
}

// ---------------------------------------------------------------------------
// Merged prep: fp32->f16 convert of x  +  both weight transposes.
// ---------------------------------------------------------------------------
__global__ __launch_bounds__(256) void prep_kernel(const float* __restrict__ x,
                                                   half_t* __restrict__ xh,
                                                   const float* __restrict__ wa,
                                                   half_t* __restrict__ waT,
                                                   const float* __restrict__ wp,
                                                   half_t* __restrict__ wpT) {
    const int blk = blockIdx.x;
    const int tid = threadIdx.x;

    if (blk < 4096) {   // x convert: 8 elems/thread
        const int i = blk * 256 + tid;
        const float4 a = *(const float4*)(x + (size_t)i * 8);
        const float4 b = *(const float4*)(x + (size_t)i * 8 + 4);
        const pk16x2 h0 = __builtin_amdgcn_cvt_pkrtz(a.x, a.y);
        const pk16x2 h1 = __builtin_amdgcn_cvt_pkrtz(a.z, a.w);
        const pk16x2 h2 = __builtin_amdgcn_cvt_pkrtz(b.x, b.y);
        const pk16x2 h3 = __builtin_amdgcn_cvt_pkrtz(b.z, b.w);
        half8 o = {(_Float16)h0.x, (_Float16)h0.y, (_Float16)h1.x, (_Float16)h1.y,
                   (_Float16)h2.x, (_Float16)h2.y, (_Float16)h3.x, (_Float16)h3.y};
        *(half8*)(xh + (size_t)i * 8) = o;
        return;
    }

    // weight transpose: W[K][N] f32 -> WT[N][K] f16, 64x64 tile
    const float* W;
    half_t* WT;
    int K, N, bb;
    if (blk < 4096 + 768) {
        bb = blk - 4096; W = wa; WT = waT; K = 1024; N = 3072;
    } else {
        bb = blk - 4864; W = wp; WT = wpT; K = 1024; N = 1024;
    }
    const int ntiles = N / 64;
    const int n0 = (bb % ntiles) * 64;
    const int k0 = (bb / ntiles) * 64;

    __shared__ float t[64][65];
    const int r = tid >> 4, c4 = (tid & 15) * 4;
#pragma unroll
    for (int p = 0; p < 4; ++p) {
        const float4 g = *(const float4*)(W + (size_t)(k0 + p * 16 + r) * N + n0 + c4);
        t[p * 16 + r][c4 + 0] = g.x;
        t[p * 16 + r][c4 + 1] = g.y;
        t[p * 16 + r][c4 + 2] = g.z;
        t[p * 16 + r][c4 + 3] = g.w;
    }
    __syncthreads();
#pragma unroll
    for (int p = 0; p < 4; ++p) {
        const int n = p * 16 + r;
        half4 s = {(_Float16)t[c4 + 0][n], (_Float16)t[c4 + 1][n],
                   (_Float16)t[c4 + 2][n], (_Float16)t[c4 + 3][n]};
        *(half4*)(WT + (size_t)(n0 + n) * K + k0 + c4) = s;
    }
}

// ---------------------------------------------------------------------------
// 256x256 f16 MFMA GEMM, BK=32, 64 KiB dbuf LDS -> 2 blocks/CU co-resident.
//   C[M,N] = A[M,K] @ Bt[N,K]^T, f16 out.
// QKV grid = 384 blocks, capacity = 512 -> ALL blocks co-resident (zero tail);
// the second block's waves fill this block's barrier stalls (m97/m114).
// Per K-tile (32 tiles at K=1024):
//   stage A(t+1)->An; 12 swizzled ds_read_b128; 32 MFMA (setprio);
//   barrier  [all fb consumed -> Bc writable];
//   stage B(t+2)->Bc; vmcnt(2) [B(t+2) stays in flight]; barrier.
// Swizzle (64 B rows, 4 chunks): global chunk g of row r stored at LDS chunk
// g^((r>>1)&3); reads use the same involution -> 2-way max (free).
// ---------------------------------------------------------------------------
__global__ __launch_bounds__(512, 4) void gemm256k(const half_t* __restrict__ A,
                                                   const half_t* __restrict__ Bt,
                                                   half_t* __restrict__ Cout,
                                                   int M, int N, int K) {
    // halfs: A0 [0,8192) B0 [8192,16384) A1 [16384,24576) B1 [24576,32768)
    __shared__ __align__(16) half_t SM[32768];   // 64 KiB

    const int tid  = threadIdx.x;
    const int lane = tid & 63;
    const int wid  = tid >> 6;
    const int l16  = lane & 15;
    const int quad = lane >> 4;

    // bijective XCD swizzle (gridDim.x % 8 == 0)
    const int nwg = gridDim.x;
    const int cpx = nwg >> 3;
    const int bid = (blockIdx.x & 7) * cpx + (blockIdx.x >> 3);
    const int nbx = N >> 8;
    const int bx = bid % nbx;
    const int by = bid / nbx;
    const size_t m0 = (size_t)by << 8;
    const size_t n0 = (size_t)bx << 8;

    const int warpM = (wid >> 2) * 128;   // wave's M half
    const int wn    = (wid & 3) * 64;     // wave's 64-col N slice
    const int NTk   = K >> 5;             // BK=32

    // staging: thread t covers row (tid>>2) within a 128-row call,
    // LDS chunk (tid&3); global chunk = (tid&3)^((tid>>3)&3)  [involution]
    const int srow = tid >> 2;            // 0..127
    const int scsw = (tid & 3) ^ ((tid >> 3) & 3);
    const half_t* gAs = A  + (m0 + srow) * (size_t)K + scsw * 8;
    const half_t* gBs = Bt + (n0 + srow) * (size_t)K + scsw * 8;

    half_t* const A0 = SM;
    half_t* const B0 = SM + 8192;
    half_t* const A1 = SM + 16384;
    half_t* const B1 = SM + 24576;

    f32x4 acc[8][4];
#pragma unroll
    for (int i = 0; i < 8; ++i)
#pragma unroll
        for (int j = 0; j < 4; ++j) acc[i][j] = (f32x4){0.f, 0.f, 0.f, 0.f};

    // swizzled fragment loads: row r, global k-chunk = quad;
    // LDS chunk = quad ^ ((r>>1)&3) = quad ^ ((l16>>1)&3)  (row bases %16==0)
    auto ldA = [&](const half_t* Ab, int mt) -> half8 {
        const int r = warpM + mt * 16 + l16;
        const int c = quad ^ ((l16 >> 1) & 3);
        return *(const half8*)(Ab + r * 32 + c * 8);
    };
    auto ldB = [&](const half_t* Bb, int nt) -> half8 {
        const int r = wn + nt * 16 + l16;
        const int c = quad ^ ((l16 >> 1) & 3);
        return *(const half8*)(Bb + r * 32 + c * 8);
    };

    // ---- prologue: A(0),B(0)->buf0, B(1)->buf1; vmcnt(2) keeps B(1) in flight
    stage16(gAs,                        A0 + wid * 512);
    stage16(gAs + (size_t)128 * K,      A0 + 4096 + wid * 512);
    stage16(gBs,                        B0 + wid * 512);
    stage16(gBs + (size_t)128 * K,      B0 + 4096 + wid * 512);
    if (NTk > 1) {
        stage16(gBs + 32,                    B1 + wid * 512);
        stage16(gBs + (size_t)128 * K + 32,  B1 + 4096 + wid * 512);
        asm volatile("s_waitcnt vmcnt(2)" ::: "memory");
    } else {
        asm volatile("s_waitcnt vmcnt(0)" ::: "memory");
    }
    __builtin_amdgcn_s_barrier();
    __builtin_amdgcn_sched_barrier(0);

    auto tile_body = [&](int t, half_t* Ac, half_t* Bc, half_t* An) {
        const int kA = (t + 1) * 32;
        const int kB = (t + 2) * 32;
        const bool doA = (t + 1) < NTk;
        const bool doB = (t + 2) < NTk;

        // stage A(t+1) -> An (dead region: A(t-1) consumed before prev barrier)
        if (doA) {
            stage16(gAs + kA,                   An + wid * 512);
            stage16(gAs + (size_t)128 * K + kA, An + 4096 + wid * 512);
        }
        // fragment reads (data guaranteed by prev tile's vmcnt+barrier)
        half8 fb[4], fa[8];
#pragma unroll
        for (int nt = 0; nt < 4; ++nt) fb[nt] = ldB(Bc, nt);
#pragma unroll
        for (int mt = 0; mt < 8; ++mt) fa[mt] = ldA(Ac, mt);

        __builtin_amdgcn_s_setprio(1);
#pragma unroll
        for (int mt = 0; mt < 8; ++mt)
#pragma unroll
            for (int nt = 0; nt < 4; ++nt)
                acc[mt][nt] = __builtin_amdgcn_mfma_f32_16x16x32_f16(
                    fa[mt], fb[nt], acc[mt][nt], 0, 0, 0);
        __builtin_amdgcn_s_setprio(0);

        __builtin_amdgcn_s_barrier();   // all waves consumed fb -> Bc writable

        if (doB) {
            stage16(gBs + kB,                   Bc + wid * 512);
            stage16(gBs + (size_t)128 * K + kB, Bc + 4096 + wid * 512);
            asm volatile("s_waitcnt vmcnt(2)" ::: "memory");   // A(t+1) landed
        } else if (doA) {
            asm volatile("s_waitcnt vmcnt(0)" ::: "memory");
        }
        __builtin_amdgcn_s_barrier();
        __builtin_amdgcn_sched_barrier(0);
    };

    for (int tt = 0; tt < NTk; tt += 2) {
        tile_body(tt, A0, B0, A1);
        if (tt + 1 < NTk)
            tile_body(tt + 1, A1, B1, A0);
    }

    // ---- epilogue: coalesced f16 stores via per-wave LDS transpose bounce ----
    __syncthreads();
    float* cw = (float*)SM + wid * 1024;   // 4 KB/wave scratch
    const int rrow = lane >> 2;            // 0..15
    const int cseg = (lane & 3) * 16;      // 0,16,32,48
#pragma unroll
    for (int mt = 0; mt < 8; ++mt) {
#pragma unroll
        for (int nt = 0; nt < 4; ++nt)
            *(f32x4*)&cw[(nt * 16 + l16) * 16 + quad * 4] = acc[mt][nt];
        // wave-internal LDS dep: DS ops are processed in order per wave
        half_t tmp[16];
#pragma unroll
        for (int jj = 0; jj < 16; ++jj)
            tmp[jj] = (half_t)cw[(cseg + jj) * 16 + rrow];
        half_t* dst = Cout + (m0 + warpM + mt * 16 + rrow) * (size_t)N + n0 + wn + cseg;
        *(half8*)(dst)     = *(const half8*)(tmp);
        *(half8*)(dst + 8) = *(const half8*)(tmp + 8);
    }
}

// ---------------------------------------------------------------------------
// 128x256 multi-phase f16 MFMA GEMM (for proj: 256 blocks = 1 full round).
// f32 out. Proven structure, unchanged.
// ---------------------------------------------------------------------------
#define BK2 64

__global__ __launch_bounds__(512, 2) void gemm128f(const half_t* __restrict__ A,
                                                   const half_t* __restrict__ Bt,
                                                   float* __restrict__ Cout,
                                                   int M, int N, int K) {
    // halfs: A0 [0,8192) B0 [8192,24576) A1 [24576,32768) B1 [32768,49152)
    __shared__ __align__(16) half_t SM[49152];   // 96 KiB

    const int tid  = threadIdx.x;
    const int lane = tid & 63;
    const int wid  = tid >> 6;
    const int l16  = lane & 15;
    const int quad = lane >> 4;

    // bijective XCD swizzle (gridDim.x % 8 == 0)
    const int nwg = gridDim.x;
    const int cpx = nwg >> 3;
    const int bid = (blockIdx.x & 7) * cpx + (blockIdx.x >> 3);
    const int nbx = N >> 8;                 // 256-col tiles
    const int bx = bid % nbx;
    const int by = bid / nbx;
    const size_t m0 = (size_t)by << 7;      // 128-row tiles
    const size_t n0 = (size_t)bx << 8;

    const int warpM = (wid >> 2) * 64;      // wave's M half (64 rows)
    const int wn    = (wid & 3) * 64;       // wave's 64-col N slice
    const int NTk   = K >> 6;

    const int srow = tid >> 3;
    const int scsw = (tid & 7) ^ (srow & 7);
    const half_t* gAs = A  + (m0 + srow) * (size_t)K + scsw * 8;
    const half_t* gBs = Bt + (n0 + srow) * (size_t)K + scsw * 8;

    half_t* const A0 = SM;
    half_t* const B0 = SM + 8192;
    half_t* const A1 = SM + 24576;
    half_t* const B1 = SM + 32768;

    f32x4 acc[4][4];
#pragma unroll
    for (int i = 0; i < 4; ++i)
#pragma unroll
        for (int j = 0; j < 4; ++j) acc[i][j] = (f32x4){0.f, 0.f, 0.f, 0.f};

    auto ldA = [&](const half_t* Ab, int mt, int kk) -> half8 {
        const int r = warpM + mt * 16 + l16;
        const int c = (kk * 4 + quad) ^ (l16 & 7);
        return *(const half8*)(Ab + r * 64 + c * 8);
    };
    auto ldB = [&](const half_t* Bb, int nt, int kk) -> half8 {
        const int r = wn + nt * 16 + l16;
        const int c = (kk * 4 + quad) ^ (l16 & 7);
        return *(const half8*)(Bb + r * 64 + c * 8);
    };

    // ---- prologue: tile0 A(2)+B(4)->buf0, tile1 B(4)->buf1; vmcnt(4)
#pragma unroll
    for (int s = 0; s < 2; ++s)
        stage16(gAs + (size_t)(s * 64) * K, A0 + s * 4096 + wid * 512);
#pragma unroll
    for (int s = 0; s < 4; ++s)
        stage16(gBs + (size_t)(s * 64) * K, B0 + s * 4096 + wid * 512);
    if (NTk > 1) {
#pragma unroll
        for (int s = 0; s < 4; ++s)
            stage16(gBs + (size_t)(s * 64) * K + BK2, B1 + s * 4096 + wid * 512);
        asm volatile("s_waitcnt vmcnt(4)" ::: "memory");
    } else {
        asm volatile("s_waitcnt vmcnt(0)" ::: "memory");
    }
    __builtin_amdgcn_s_barrier();
    __builtin_amdgcn_sched_barrier(0);

    auto tile_body = [&](int t, half_t* Ac, half_t* Bc, half_t* An) {
        const int kA = (t + 1) * BK2;
        const int kB = (t + 2) * BK2;
        const bool doA = (t + 1) < NTk;
        const bool doB = (t + 2) < NTk;

        half8 fb[4][2];

        // ---- phase A: stage A(t+1) [2]; read ALL B-frags + A mt0/mt1; MFMA
        if (doA) {
            stage16(gAs + (size_t)(0 * 64) * K + kA, An + 0 * 4096 + wid * 512);
            stage16(gAs + (size_t)(1 * 64) * K + kA, An + 1 * 4096 + wid * 512);
        }
#pragma unroll
        for (int nt = 0; nt < 4; ++nt) {
            fb[nt][0] = ldB(Bc, nt, 0);
            fb[nt][1] = ldB(Bc, nt, 1);
        }
        {
            half8 a00 = ldA(Ac, 0, 0), a01 = ldA(Ac, 0, 1);
            half8 a10 = ldA(Ac, 1, 0), a11 = ldA(Ac, 1, 1);
            __builtin_amdgcn_s_barrier();
            __builtin_amdgcn_s_setprio(1);
#pragma unroll
            for (int nt = 0; nt < 4; ++nt) {
                acc[0][nt] = __builtin_amdgcn_mfma_f32_16x16x32_f16(a00, fb[nt][0], acc[0][nt], 0, 0, 0);
                acc[0][nt] = __builtin_amdgcn_mfma_f32_16x16x32_f16(a01, fb[nt][1], acc[0][nt], 0, 0, 0);
                acc[1][nt] = __builtin_amdgcn_mfma_f32_16x16x32_f16(a10, fb[nt][0], acc[1][nt], 0, 0, 0);
                acc[1][nt] = __builtin_amdgcn_mfma_f32_16x16x32_f16(a11, fb[nt][1], acc[1][nt], 0, 0, 0);
            }
            __builtin_amdgcn_s_setprio(0);
        }
        // ---- phase B: stage B(t+2) [4] into Bc (fb fully read); A mt2/mt3; MFMA
        if (doB) {
#pragma unroll
            for (int s = 0; s < 4; ++s)
                stage16(gBs + (size_t)(s * 64) * K + kB, Bc + s * 4096 + wid * 512);
        }
        {
            half8 a00 = ldA(Ac, 2, 0), a01 = ldA(Ac, 2, 1);
            half8 a10 = ldA(Ac, 3, 0), a11 = ldA(Ac, 3, 1);
            __builtin_amdgcn_s_barrier();
            __builtin_amdgcn_s_setprio(1);
#pragma unroll
            for (int nt = 0; nt < 4; ++nt) {
                acc[2][nt] = __builtin_amdgcn_mfma_f32_16x16x32_f16(a00, fb[nt][0], acc[2][nt], 0, 0, 0);
                acc[2][nt] = __builtin_amdgcn_mfma_f32_16x16x32_f16(a01, fb[nt][1], acc[2][nt], 0, 0, 0);
                acc[3][nt] = __builtin_amdgcn_mfma_f32_16x16x32_f16(a10, fb[nt][0], acc[3][nt], 0, 0, 0);
                acc[3][nt] = __builtin_amdgcn_mfma_f32_16x16x32_f16(a11, fb[nt][1], acc[3][nt], 0, 0, 0);
            }
            __builtin_amdgcn_s_setprio(0);
        }
        // ---- tile end: counted vmcnt
        if (doB) {
            asm volatile("s_waitcnt vmcnt(4)" ::: "memory");
        } else if (doA) {
            asm volatile("s_waitcnt vmcnt(0)" ::: "memory");
        }
        __builtin_amdgcn_s_barrier();
        __builtin_amdgcn_sched_barrier(0);
    };

    for (int tt = 0; tt < NTk; tt += 2) {
        tile_body(tt, A0, B0, A1);
        if (tt + 1 < NTk)
            tile_body(tt + 1, A1, B1, A0);
    }

    // ---- epilogue: f32 direct coalesced-per-quad stores ----
#pragma unroll
    for (int mt = 0; mt < 4; ++mt)
#pragma unroll
        for (int nt = 0; nt < 4; ++nt)
#pragma unroll
            for (int r = 0; r < 4; ++r) {
                const size_t row = m0 + warpM + mt * 16 + quad * 4 + r;
                const size_t col = n0 + wn + nt * 16 + l16;
                Cout[row * (size_t)N + col] = acc[mt][nt][r];
            }
}

// ---------------------------------------------------------------------------
// MFMA flash attention v5: Q-tile 128 (4 waves x 32 q-rows), Bc=64.
// Unchanged from round 4/5.
// ---------------------------------------------------------------------------
#define SCALE_EXP2 0.18033688f   // 0.125 * log2(e)

__global__ __launch_bounds__(256, 2) void attn_mfma(const half_t* __restrict__ qkv,
                                                    half_t* __restrict__ y) {
    __shared__ __align__(16) half_t Kl[64 * 64];
    __shared__ __align__(16) half_t Vt[64 * 64];
    __shared__ float Lstat[128];

    const int tid  = threadIdx.x;
    const int wid  = tid >> 6;
    const int lane = tid & 63;
    const int l16  = lane & 15;
    const int quad = lane >> 4;

    const int L = blockIdx.x;
    const int g = L & 63;                 // (b,h) group -> fixed XCD (g % 8)
    const int s = L >> 6;                 // pair slot 0..7
    const int h = g & 15;
    const int b = g >> 4;

    const size_t rs = 3 * C_EMB;
    const half_t* qb = qkv + (size_t)b * T_SEQ * rs + h * HS;
    const half_t* kb = qb + C_EMB;
    const half_t* vb = qb + 2 * C_EMB;

    const int srow = tid >> 2;            // 0..63
    const int scol = (tid & 3) * 16;      // 0,16,32,48 (halfs, global)
    const int sc2  = (tid & 3) * 2;       // LDS chunk pair base (16B chunks)
    const int rp   = tid & 31;            // row pair: rows 2rp, 2rp+1
    const int dblk = tid >> 5;            // 0..7 -> d = dblk*8 .. +8

    const int wq = wid * 32;              // wave's 32-q base within 128 tile

    // swizzled addressing: 16B chunk c of row r lives at chunk c^(r&7)
    auto kswz = [&](int row, int chunk) -> half_t* {
        return Kl + row * 64 + ((chunk ^ (row & 7)) << 3);
    };
    auto vswz = [&](int row, int chunk) -> half_t* {
        return Vt + row * 64 + ((chunk ^ (row & 7)) << 3);
    };

#pragma unroll 1
    for (int j = 0; j < 2; ++j) {
        const int jj = (j == 0) ? (15 - s) : s;   // 128-row job index 0..15
        const int q0 = jj * 128;
        const int ntk = 2 * jj + 2;               // k-tiles 0..2jj+1

        // ---- Q direct global -> regs (two 16-row subsets per wave) ----
        half8 aQ[2][2];
#pragma unroll
        for (int qs = 0; qs < 2; ++qs)
#pragma unroll
            for (int s2 = 0; s2 < 2; ++s2)
                aQ[qs][s2] = *(const half8*)(qb +
                    (size_t)(q0 + wq + qs * 16 + l16) * rs + s2 * 32 + quad * 8);

        // ---- prefetch k-tile 0 K/V into regs ----
        const half_t* kptr = kb + (size_t)srow * rs + scol;
        const half_t* vptr = vb + (size_t)(2 * rp) * rs + dblk * 8;
        half8 kp0, kp1;
        uint4 vpa, vpc;
        kp0 = *(const half8*)(kptr);
        kp1 = *(const half8*)(kptr + 8);
        vpa = *(const uint4*)(vptr);
        vpc = *(const uint4*)(vptr + rs);

        f32x4 O[2][4];
#pragma unroll
        for (int qs = 0; qs < 2; ++qs)
#pragma unroll
            for (int dt = 0; dt < 4; ++dt) O[qs][dt] = (f32x4){0.f, 0.f, 0.f, 0.f};
        float lw[2] = {0.f, 0.f};

        for (int kt = 0; kt < ntk; ++kt) {
            __syncthreads();   // prior tile frag reads / prior epilogue reads done

            // ---- write prefetched K: Kl[kcol][d], swizzled ----
            *(half8*)kswz(srow, sc2)     = kp0;
            *(half8*)kswz(srow, sc2 + 1) = kp1;
            // ---- write prefetched V^T: Vt[d][kcol], paired-row b32 packing ----
            {
                const uint32_t a0[4] = {vpa.x, vpa.y, vpa.z, vpa.w};
                const uint32_t c0[4] = {vpc.x, vpc.y, vpc.z, vpc.w};
#pragma unroll
                for (int u = 0; u < 4; ++u) {
                    const int d0 = dblk * 8 + 2 * u;
                    const uint32_t w0 = (a0[u] & 0xffffu) | (c0[u] << 16);
                    const uint32_t w1 = (a0[u] >> 16) | (c0[u] & 0xffff0000u);
                    *(uint32_t*)((unsigned short*)vswz(d0,     rp >> 2) + (rp & 3) * 2) = w0;
                    *(uint32_t*)((unsigned short*)vswz(d0 + 1, rp >> 2) + (rp & 3) * 2) = w1;
                }
            }
            __syncthreads();

            // ---- T14: issue next tile's loads (increment-only addressing) ----
            if (kt + 1 < ntk) {
                kptr += 64 * rs;
                vptr += 64 * rs;
                kp0 = *(const half8*)(kptr);
                kp1 = *(const half8*)(kptr + 8);
                vpa = *(const uint4*)(vptr);
                vpc = *(const uint4*)(vptr + rs);
            }

            const bool dmask = (kt >= ntk - 2);   // last two tiles may need mask

            // ---- fused: S^T MFMA -> exp2 -> P frag -> O += P@V, two q-subsets ----
#pragma unroll
            for (int mt = 0; mt < 4; ++mt) {
                const half8 aK0 = *(const half8*)kswz(mt * 16 + l16, quad);
                const half8 aK1 = *(const half8*)kswz(mt * 16 + l16, 4 + quad);
                half4 bV[4];
#pragma unroll
                for (int dt = 0; dt < 4; ++dt)
                    bV[dt] = *(const half4*)(vswz(dt * 16 + l16, 2 * mt + (quad >> 1)) +
                                             (quad & 1) * 4);
                const int kbase = kt * 64 + mt * 16 + quad * 4;   // global k of p[0]
#pragma unroll
                for (int qs = 0; qs < 2; ++qs) {
                    f32x4 sa = (f32x4){0.f, 0.f, 0.f, 0.f};
                    sa = __builtin_amdgcn_mfma_f32_16x16x32_f16(aK0, aQ[qs][0], sa, 0, 0, 0);
                    sa = __builtin_amdgcn_mfma_f32_16x16x32_f16(aK1, aQ[qs][1], sa, 0, 0, 0);

                    float p[4];
#pragma unroll
                    for (int r = 0; r < 4; ++r)
                        p[r] = __builtin_amdgcn_exp2f(sa[r] * SCALE_EXP2);
                    if (dmask) {
                        const int qg = q0 + wq + qs * 16 + l16;   // global q row
#pragma unroll
                        for (int r = 0; r < 4; ++r)
                            if (kbase + r > qg) p[r] = 0.f;
                    }
                    lw[qs] += (p[0] + p[1]) + (p[2] + p[3]);

                    const half4 pa = {(_Float16)p[0], (_Float16)p[1],
                                      (_Float16)p[2], (_Float16)p[3]};
#pragma unroll
                    for (int dt = 0; dt < 4; ++dt)
                        O[qs][dt] = mfma_k16(pa, bV[dt], O[qs][dt]);
                }
            }
        }

        // ---- epilogue: l-reduce, normalize, coalesced store via LDS (2 passes) ----
#pragma unroll
        for (int qs = 0; qs < 2; ++qs) {
            lw[qs] += __shfl_xor(lw[qs], 16);
            lw[qs] += __shfl_xor(lw[qs], 32);
            if (quad == 0) Lstat[wq + qs * 16 + l16] = lw[qs];
        }
        __syncthreads();   // all waves done reading Vt/Kl; Lstat visible

        // pass A: q-rows 0..63 (waves 0,1)
        if (wid < 2) {
#pragma unroll
            for (int qs = 0; qs < 2; ++qs)
#pragma unroll
                for (int r = 0; r < 4; ++r) {
                    const int rowl = wq + qs * 16 + quad * 4 + r;   // 0..63
                    const float inv = 1.f / Lstat[rowl];
#pragma unroll
                    for (int dt = 0; dt < 4; ++dt)
                        *(vswz(rowl, 2 * dt + (l16 >> 3)) + (l16 & 7)) =
                            (half_t)(O[qs][dt][r] * inv);
                }
        }
        __syncthreads();
        {
            half_t* dst = y + ((size_t)b * T_SEQ + q0 + srow) * C_EMB + h * HS + scol;
            *(half8*)(dst)     = *(const half8*)vswz(srow, sc2);
            *(half8*)(dst + 8) = *(const half8*)vswz(srow, sc2 + 1);
        }
        __syncthreads();

        // pass B: q-rows 64..127 (waves 2,3)
        if (wid >= 2) {
#pragma unroll
            for (int qs = 0; qs < 2; ++qs)
#pragma unroll
                for (int r = 0; r < 4; ++r) {
                    const int rowg = wq + qs * 16 + quad * 4 + r;   // 64..127
                    const float inv = 1.f / Lstat[rowg];
#pragma unroll
                    for (int dt = 0; dt < 4; ++dt)
                        *(vswz(rowg - 64, 2 * dt + (l16 >> 3)) + (l16 & 7)) =
                            (half_t)(O[qs][dt][r] * inv);
                }
        }
        __syncthreads();
        {
            half_t* dst = y + ((size_t)b * T_SEQ + q0 + 64 + srow) * C_EMB + h * HS + scol;
            *(half8*)(dst)     = *(const half8*)vswz(srow, sc2);
            *(half8*)(dst + 8) = *(const half8*)vswz(srow, sc2 + 1);
        }
    }
}

// ---------------------------------------------------------------------------
extern "C" void kernel_launch(void* const* d_in, const int* in_sizes, int n_in,
                              void* d_out, int out_size, void* d_ws, size_t ws_size,
                              hipStream_t stream) {
    const float* x      = (const float*)d_in[0];   // [8192,1024]
    const float* w_attn = (const float*)d_in[1];   // [1024,3072]
    const float* w_proj = (const float*)d_in[2];   // [1024,1024]
    float* out = (float*)d_out;

    half_t* xh   = (half_t*)d_ws;                        // 16 MB
    half_t* waT  = xh   + (size_t)8192 * 1024;           //  6 MB [3072][1024]
    half_t* wpT  = waT  + (size_t)3072 * 1024;           //  2 MB [1024][1024]
    half_t* qkvh = wpT  + (size_t)1024 * 1024;           // 48 MB [8192][3072]
    half_t* yh   = qkvh + (size_t)8192 * 3072;           // 16 MB [8192][1024]

    // merged prep: x convert + both weight transposes
    prep_kernel<<<5120, 256, 0, stream>>>(x, xh, w_attn, waT, w_proj, wpT);

    // qkv = x @ w_attn   (256x256 BK=32, 2 blocks/CU, 384 blocks all resident)
    gemm256k<<<dim3(384), 512, 0, stream>>>(xh, waT, qkvh, 8192, 3072, 1024);

    // attention v5 (512 balanced 128-q blocks, XCD-swizzled)
    attn_mfma<<<dim3(512), 256, 0, stream>>>(qkvh, yh);

    // out = y @ w_proj   (128x256 template, 256 blocks = 1 full round, f32 out)
    gemm128f<<<dim3(256), 512, 0, stream>>>(yh, wpT, out, 8192, 1024, 1024);
}

// Round 7
// 255.233 us; speedup vs baseline: 2.8259x; 2.8259x over previous
//
#include <hip/hip_runtime.h>
#include <math.h>
#include <stdint.h>

#define B_BATCH 4
#define T_SEQ   2048
#define C_EMB   1024
#define NH      16
#define HS      64

typedef _Float16 half_t;
typedef __attribute__((ext_vector_type(8))) _Float16 half8;   // 4 VGPRs, 16 B
typedef __attribute__((ext_vector_type(4))) _Float16 half4;   // 2 VGPRs, 8 B
typedef __attribute__((ext_vector_type(2))) __fp16 pk16x2;    // cvt_pkrtz result type
typedef __attribute__((ext_vector_type(4))) float f32x4;

// K=16 f16 MFMA; fallback = zero-padded K=32 (A/B agree on slot map -> same dot)
static __device__ __forceinline__ f32x4 mfma_k16(half4 a, half4 b, f32x4 c) {
#if __has_builtin(__builtin_amdgcn_mfma_f32_16x16x16f16)
    return __builtin_amdgcn_mfma_f32_16x16x16f16(a, b, c, 0, 0, 0);
#else
    half8 a8 = {a.x, a.y, a.z, a.w, (_Float16)0, (_Float16)0, (_Float16)0, (_Float16)0};
    half8 b8 = {b.x, b.y, b.z, b.w, (_Float16)0, (_Float16)0, (_Float16)0, (_Float16)0};
    return __builtin_amdgcn_mfma_f32_16x16x32_f16(a8, b8, c, 0, 0, 0);
#endif
}

// async global->LDS, 16B/lane; LDS dest = wave-uniform base + lane*16
static __device__ __forceinline__ void stage16(const void* g, void* lds_base) {
#if __has_builtin(__builtin_amdgcn_global_load_lds)
    __builtin_amdgcn_global_load_lds(
        (const __attribute__((address_space(1))) void*)g,
        (__attribute__((address_space(3))) void*)lds_base, 16, 0, 0);
#else
    const int lane = threadIdx.x & 63;
    ((uint4*)lds_base)[lane] = *(const uint4*)g;
#endif
}

// ---------------------------------------------------------------------------
// Merged prep: fp32->f16 convert of x  +  both weight transposes.
// ---------------------------------------------------------------------------
__global__ __launch_bounds__(256) void prep_kernel(const float* __restrict__ x,
                                                   half_t* __restrict__ xh,
                                                   const float* __restrict__ wa,
                                                   half_t* __restrict__ waT,
                                                   const float* __restrict__ wp,
                                                   half_t* __restrict__ wpT) {
    const int blk = blockIdx.x;
    const int tid = threadIdx.x;

    if (blk < 4096) {   // x convert: 8 elems/thread
        const int i = blk * 256 + tid;
        const float4 a = *(const float4*)(x + (size_t)i * 8);
        const float4 b = *(const float4*)(x + (size_t)i * 8 + 4);
        const pk16x2 h0 = __builtin_amdgcn_cvt_pkrtz(a.x, a.y);
        const pk16x2 h1 = __builtin_amdgcn_cvt_pkrtz(a.z, a.w);
        const pk16x2 h2 = __builtin_amdgcn_cvt_pkrtz(b.x, b.y);
        const pk16x2 h3 = __builtin_amdgcn_cvt_pkrtz(b.z, b.w);
        half8 o = {(_Float16)h0.x, (_Float16)h0.y, (_Float16)h1.x, (_Float16)h1.y,
                   (_Float16)h2.x, (_Float16)h2.y, (_Float16)h3.x, (_Float16)h3.y};
        *(half8*)(xh + (size_t)i * 8) = o;
        return;
    }

    // weight transpose: W[K][N] f32 -> WT[N][K] f16, 64x64 tile
    const float* W;
    half_t* WT;
    int K, N, bb;
    if (blk < 4096 + 768) {
        bb = blk - 4096; W = wa; WT = waT; K = 1024; N = 3072;
    } else {
        bb = blk - 4864; W = wp; WT = wpT; K = 1024; N = 1024;
    }
    const int ntiles = N / 64;
    const int n0 = (bb % ntiles) * 64;
    const int k0 = (bb / ntiles) * 64;

    __shared__ float t[64][65];
    const int r = tid >> 4, c4 = (tid & 15) * 4;
#pragma unroll
    for (int p = 0; p < 4; ++p) {
        const float4 g = *(const float4*)(W + (size_t)(k0 + p * 16 + r) * N + n0 + c4);
        t[p * 16 + r][c4 + 0] = g.x;
        t[p * 16 + r][c4 + 1] = g.y;
        t[p * 16 + r][c4 + 2] = g.z;
        t[p * 16 + r][c4 + 3] = g.w;
    }
    __syncthreads();
#pragma unroll
    for (int p = 0; p < 4; ++p) {
        const int n = p * 16 + r;
        half4 s = {(_Float16)t[c4 + 0][n], (_Float16)t[c4 + 1][n],
                   (_Float16)t[c4 + 2][n], (_Float16)t[c4 + 3][n]};
        *(half4*)(WT + (size_t)(n0 + n) * K + k0 + c4) = s;
    }
}

// ---------------------------------------------------------------------------
// 256x256 multi-phase f16 MFMA GEMM — PROVEN 74.6 us for QKV shape.
// launch_bounds(512,2): 256-reg cap, acc stays in AGPRs (VGPR_Count 120).
// ---------------------------------------------------------------------------
#define BK2 64

__global__ __launch_bounds__(512, 2) void gemm256(const half_t* __restrict__ A,
                                                  const half_t* __restrict__ Bt,
                                                  half_t* __restrict__ Cout,
                                                  int M, int N, int K) {
    // buf0: A [0,16384), B [16384,32768); buf1: A [32768,49152), B [49152,65536)
    __shared__ __align__(16) half_t SM[65536];   // 128 KiB

    const int tid  = threadIdx.x;
    const int lane = tid & 63;
    const int wid  = tid >> 6;
    const int l16  = lane & 15;
    const int quad = lane >> 4;

    // bijective XCD swizzle (gridDim.x % 8 == 0)
    const int nwg = gridDim.x;
    const int cpx = nwg >> 3;
    const int bid = (blockIdx.x & 7) * cpx + (blockIdx.x >> 3);
    const int nbx = N >> 8;
    const int bx = bid % nbx;
    const int by = bid / nbx;
    const size_t m0 = (size_t)by << 8;
    const size_t n0 = (size_t)bx << 8;

    const int warpM = (wid >> 2) * 128;   // wave's M half
    const int wn    = (wid & 3) * 64;     // wave's 64-col N slice
    const int NTk   = K >> 6;

    // staging: thread t covers row (tid>>3), swizzled chunk (tid&7)^((tid>>3)&7)
    const int srow = tid >> 3;
    const int scsw = (tid & 7) ^ (srow & 7);
    const half_t* gAs = A  + (m0 + srow) * (size_t)K + scsw * 8;
    const half_t* gBs = Bt + (n0 + srow) * (size_t)K + scsw * 8;

    f32x4 acc[8][4];
#pragma unroll
    for (int i = 0; i < 8; ++i)
#pragma unroll
        for (int j = 0; j < 4; ++j) acc[i][j] = (f32x4){0.f, 0.f, 0.f, 0.f};

    // swizzled fragment loads (r&7 == l16&7 since all row bases are %8==0)
    auto ldA = [&](const half_t* Ab, int mt, int kk) -> half8 {
        const int r = warpM + mt * 16 + l16;
        const int c = (kk * 4 + quad) ^ (l16 & 7);
        return *(const half8*)(Ab + r * 64 + c * 8);
    };
    auto ldB = [&](const half_t* Bb, int nt, int kk) -> half8 {
        const int r = wn + nt * 16 + l16;
        const int c = (kk * 4 + quad) ^ (l16 & 7);
        return *(const half8*)(Bb + r * 64 + c * 8);
    };

    // ---- prologue: tile0 (A+B)->buf0, tile1 B->buf1; vmcnt(4) keeps tile1-B in flight
#pragma unroll
    for (int s = 0; s < 4; ++s)
        stage16(gAs + (size_t)(s * 64) * K, SM + s * 4096 + wid * 512);
#pragma unroll
    for (int s = 0; s < 4; ++s)
        stage16(gBs + (size_t)(s * 64) * K, SM + 16384 + s * 4096 + wid * 512);
    if (NTk > 1) {
#pragma unroll
        for (int s = 0; s < 4; ++s)
            stage16(gBs + (size_t)(s * 64) * K + BK2, SM + 49152 + s * 4096 + wid * 512);
        asm volatile("s_waitcnt vmcnt(4)" ::: "memory");
    } else {
        asm volatile("s_waitcnt vmcnt(0)" ::: "memory");
    }
    __builtin_amdgcn_s_barrier();
    __builtin_amdgcn_sched_barrier(0);

    auto tile_body = [&](int t, half_t* Ac, half_t* Bc, half_t* An) {
        const int kA = (t + 1) * BK2;
        const int kB = (t + 2) * BK2;
        const bool doA = (t + 1) < NTk;
        const bool doB = (t + 2) < NTk;

        half8 fb[4][2];

        // ---- phase 0: stage A-half0(t+1); read B-frags + A quad0; MFMA q0
        if (doA) {
            stage16(gAs + (size_t)(0 * 64) * K + kA, An + 0 * 4096 + wid * 512);
            stage16(gAs + (size_t)(1 * 64) * K + kA, An + 1 * 4096 + wid * 512);
        }
#pragma unroll
        for (int nt = 0; nt < 4; ++nt) {
            fb[nt][0] = ldB(Bc, nt, 0);
            fb[nt][1] = ldB(Bc, nt, 1);
        }
        {
            half8 a00 = ldA(Ac, 0, 0), a01 = ldA(Ac, 0, 1);
            half8 a10 = ldA(Ac, 1, 0), a11 = ldA(Ac, 1, 1);
            __builtin_amdgcn_s_barrier();
            __builtin_amdgcn_s_setprio(1);
#pragma unroll
            for (int nt = 0; nt < 4; ++nt) {
                acc[0][nt] = __builtin_amdgcn_mfma_f32_16x16x32_f16(a00, fb[nt][0], acc[0][nt], 0, 0, 0);
                acc[0][nt] = __builtin_amdgcn_mfma_f32_16x16x32_f16(a01, fb[nt][1], acc[0][nt], 0, 0, 0);
                acc[1][nt] = __builtin_amdgcn_mfma_f32_16x16x32_f16(a10, fb[nt][0], acc[1][nt], 0, 0, 0);
                acc[1][nt] = __builtin_amdgcn_mfma_f32_16x16x32_f16(a11, fb[nt][1], acc[1][nt], 0, 0, 0);
            }
            __builtin_amdgcn_s_setprio(0);
        }
        // ---- phase 1: stage A-half1(t+1); A quad1; MFMA q1
        if (doA) {
            stage16(gAs + (size_t)(2 * 64) * K + kA, An + 2 * 4096 + wid * 512);
            stage16(gAs + (size_t)(3 * 64) * K + kA, An + 3 * 4096 + wid * 512);
        }
        {
            half8 a00 = ldA(Ac, 2, 0), a01 = ldA(Ac, 2, 1);
            half8 a10 = ldA(Ac, 3, 0), a11 = ldA(Ac, 3, 1);
            __builtin_amdgcn_s_barrier();
            __builtin_amdgcn_s_setprio(1);
#pragma unroll
            for (int nt = 0; nt < 4; ++nt) {
                acc[2][nt] = __builtin_amdgcn_mfma_f32_16x16x32_f16(a00, fb[nt][0], acc[2][nt], 0, 0, 0);
                acc[2][nt] = __builtin_amdgcn_mfma_f32_16x16x32_f16(a01, fb[nt][1], acc[2][nt], 0, 0, 0);
                acc[3][nt] = __builtin_amdgcn_mfma_f32_16x16x32_f16(a10, fb[nt][0], acc[3][nt], 0, 0, 0);
                acc[3][nt] = __builtin_amdgcn_mfma_f32_16x16x32_f16(a11, fb[nt][1], acc[3][nt], 0, 0, 0);
            }
            __builtin_amdgcn_s_setprio(0);
        }
        // ---- phase 2: stage B-half0(t+2) into Bc; MFMA q2
        if (doB) {
            stage16(gBs + (size_t)(0 * 64) * K + kB, Bc + 0 * 4096 + wid * 512);
            stage16(gBs + (size_t)(1 * 64) * K + kB, Bc + 1 * 4096 + wid * 512);
        }
        {
            half8 a00 = ldA(Ac, 4, 0), a01 = ldA(Ac, 4, 1);
            half8 a10 = ldA(Ac, 5, 0), a11 = ldA(Ac, 5, 1);
            __builtin_amdgcn_s_barrier();
            __builtin_amdgcn_s_setprio(1);
#pragma unroll
            for (int nt = 0; nt < 4; ++nt) {
                acc[4][nt] = __builtin_amdgcn_mfma_f32_16x16x32_f16(a00, fb[nt][0], acc[4][nt], 0, 0, 0);
                acc[4][nt] = __builtin_amdgcn_mfma_f32_16x16x32_f16(a01, fb[nt][1], acc[4][nt], 0, 0, 0);
                acc[5][nt] = __builtin_amdgcn_mfma_f32_16x16x32_f16(a10, fb[nt][0], acc[5][nt], 0, 0, 0);
                acc[5][nt] = __builtin_amdgcn_mfma_f32_16x16x32_f16(a11, fb[nt][1], acc[5][nt], 0, 0, 0);
            }
            __builtin_amdgcn_s_setprio(0);
        }
        // ---- phase 3: stage B-half1(t+2); MFMA q3
        if (doB) {
            stage16(gBs + (size_t)(2 * 64) * K + kB, Bc + 2 * 4096 + wid * 512);
            stage16(gBs + (size_t)(3 * 64) * K + kB, Bc + 3 * 4096 + wid * 512);
        }
        {
            half8 a00 = ldA(Ac, 6, 0), a01 = ldA(Ac, 6, 1);
            half8 a10 = ldA(Ac, 7, 0), a11 = ldA(Ac, 7, 1);
            __builtin_amdgcn_s_barrier();
            __builtin_amdgcn_s_setprio(1);
#pragma unroll
            for (int nt = 0; nt < 4; ++nt) {
                acc[6][nt] = __builtin_amdgcn_mfma_f32_16x16x32_f16(a00, fb[nt][0], acc[6][nt], 0, 0, 0);
                acc[6][nt] = __builtin_amdgcn_mfma_f32_16x16x32_f16(a01, fb[nt][1], acc[6][nt], 0, 0, 0);
                acc[7][nt] = __builtin_amdgcn_mfma_f32_16x16x32_f16(a10, fb[nt][0], acc[7][nt], 0, 0, 0);
                acc[7][nt] = __builtin_amdgcn_mfma_f32_16x16x32_f16(a11, fb[nt][1], acc[7][nt], 0, 0, 0);
            }
            __builtin_amdgcn_s_setprio(0);
        }
        // ---- tile end: counted vmcnt (retire A(t+1)+older; keep B(t+2) in flight)
        if (doB) {
            asm volatile("s_waitcnt vmcnt(4)" ::: "memory");
        } else if (doA) {
            asm volatile("s_waitcnt vmcnt(0)" ::: "memory");
        }
        __builtin_amdgcn_s_barrier();
        __builtin_amdgcn_sched_barrier(0);
    };

    for (int tt = 0; tt < NTk; tt += 2) {
        tile_body(tt, SM, SM + 16384, SM + 32768);
        if (tt + 1 < NTk)
            tile_body(tt + 1, SM + 32768, SM + 49152, SM);
    }

    // ---- epilogue: coalesced f16 stores via per-wave LDS transpose bounce ----
    __syncthreads();
    float* cw = (float*)SM + wid * 1024;   // 4 KB/wave scratch
    const int rrow = lane >> 2;            // 0..15
    const int cseg = (lane & 3) * 16;      // 0,16,32,48
#pragma unroll
    for (int mt = 0; mt < 8; ++mt) {
#pragma unroll
        for (int nt = 0; nt < 4; ++nt)
            *(f32x4*)&cw[(nt * 16 + l16) * 16 + quad * 4] = acc[mt][nt];
        // wave-internal LDS dep: DS ops are processed in order per wave
        half_t tmp[16];
#pragma unroll
        for (int jj = 0; jj < 16; ++jj)
            tmp[jj] = (half_t)cw[(cseg + jj) * 16 + rrow];
        half_t* dst = Cout + (m0 + warpM + mt * 16 + rrow) * (size_t)N + n0 + wn + cseg;
        *(half8*)(dst)     = *(const half8*)(tmp);
        *(half8*)(dst + 8) = *(const half8*)(tmp + 8);
    }
}

// ---------------------------------------------------------------------------
// 128x256 multi-phase f16 MFMA GEMM (for proj: 256 blocks = 1 full round).
// f32 out. Proven structure, unchanged.
// ---------------------------------------------------------------------------
__global__ __launch_bounds__(512, 2) void gemm128f(const half_t* __restrict__ A,
                                                   const half_t* __restrict__ Bt,
                                                   float* __restrict__ Cout,
                                                   int M, int N, int K) {
    // halfs: A0 [0,8192) B0 [8192,24576) A1 [24576,32768) B1 [32768,49152)
    __shared__ __align__(16) half_t SM[49152];   // 96 KiB

    const int tid  = threadIdx.x;
    const int lane = tid & 63;
    const int wid  = tid >> 6;
    const int l16  = lane & 15;
    const int quad = lane >> 4;

    // bijective XCD swizzle (gridDim.x % 8 == 0)
    const int nwg = gridDim.x;
    const int cpx = nwg >> 3;
    const int bid = (blockIdx.x & 7) * cpx + (blockIdx.x >> 3);
    const int nbx = N >> 8;                 // 256-col tiles
    const int bx = bid % nbx;
    const int by = bid / nbx;
    const size_t m0 = (size_t)by << 7;      // 128-row tiles
    const size_t n0 = (size_t)bx << 8;

    const int warpM = (wid >> 2) * 64;      // wave's M half (64 rows)
    const int wn    = (wid & 3) * 64;       // wave's 64-col N slice
    const int NTk   = K >> 6;

    const int srow = tid >> 3;
    const int scsw = (tid & 7) ^ (srow & 7);
    const half_t* gAs = A  + (m0 + srow) * (size_t)K + scsw * 8;
    const half_t* gBs = Bt + (n0 + srow) * (size_t)K + scsw * 8;

    half_t* const A0 = SM;
    half_t* const B0 = SM + 8192;
    half_t* const A1 = SM + 24576;
    half_t* const B1 = SM + 32768;

    f32x4 acc[4][4];
#pragma unroll
    for (int i = 0; i < 4; ++i)
#pragma unroll
        for (int j = 0; j < 4; ++j) acc[i][j] = (f32x4){0.f, 0.f, 0.f, 0.f};

    auto ldA = [&](const half_t* Ab, int mt, int kk) -> half8 {
        const int r = warpM + mt * 16 + l16;
        const int c = (kk * 4 + quad) ^ (l16 & 7);
        return *(const half8*)(Ab + r * 64 + c * 8);
    };
    auto ldB = [&](const half_t* Bb, int nt, int kk) -> half8 {
        const int r = wn + nt * 16 + l16;
        const int c = (kk * 4 + quad) ^ (l16 & 7);
        return *(const half8*)(Bb + r * 64 + c * 8);
    };

    // ---- prologue: tile0 A(2)+B(4)->buf0, tile1 B(4)->buf1; vmcnt(4)
#pragma unroll
    for (int s = 0; s < 2; ++s)
        stage16(gAs + (size_t)(s * 64) * K, A0 + s * 4096 + wid * 512);
#pragma unroll
    for (int s = 0; s < 4; ++s)
        stage16(gBs + (size_t)(s * 64) * K, B0 + s * 4096 + wid * 512);
    if (NTk > 1) {
#pragma unroll
        for (int s = 0; s < 4; ++s)
            stage16(gBs + (size_t)(s * 64) * K + BK2, B1 + s * 4096 + wid * 512);
        asm volatile("s_waitcnt vmcnt(4)" ::: "memory");
    } else {
        asm volatile("s_waitcnt vmcnt(0)" ::: "memory");
    }
    __builtin_amdgcn_s_barrier();
    __builtin_amdgcn_sched_barrier(0);

    auto tile_body = [&](int t, half_t* Ac, half_t* Bc, half_t* An) {
        const int kA = (t + 1) * BK2;
        const int kB = (t + 2) * BK2;
        const bool doA = (t + 1) < NTk;
        const bool doB = (t + 2) < NTk;

        half8 fb[4][2];

        // ---- phase A: stage A(t+1) [2]; read ALL B-frags + A mt0/mt1; MFMA
        if (doA) {
            stage16(gAs + (size_t)(0 * 64) * K + kA, An + 0 * 4096 + wid * 512);
            stage16(gAs + (size_t)(1 * 64) * K + kA, An + 1 * 4096 + wid * 512);
        }
#pragma unroll
        for (int nt = 0; nt < 4; ++nt) {
            fb[nt][0] = ldB(Bc, nt, 0);
            fb[nt][1] = ldB(Bc, nt, 1);
        }
        {
            half8 a00 = ldA(Ac, 0, 0), a01 = ldA(Ac, 0, 1);
            half8 a10 = ldA(Ac, 1, 0), a11 = ldA(Ac, 1, 1);
            __builtin_amdgcn_s_barrier();
            __builtin_amdgcn_s_setprio(1);
#pragma unroll
            for (int nt = 0; nt < 4; ++nt) {
                acc[0][nt] = __builtin_amdgcn_mfma_f32_16x16x32_f16(a00, fb[nt][0], acc[0][nt], 0, 0, 0);
                acc[0][nt] = __builtin_amdgcn_mfma_f32_16x16x32_f16(a01, fb[nt][1], acc[0][nt], 0, 0, 0);
                acc[1][nt] = __builtin_amdgcn_mfma_f32_16x16x32_f16(a10, fb[nt][0], acc[1][nt], 0, 0, 0);
                acc[1][nt] = __builtin_amdgcn_mfma_f32_16x16x32_f16(a11, fb[nt][1], acc[1][nt], 0, 0, 0);
            }
            __builtin_amdgcn_s_setprio(0);
        }
        // ---- phase B: stage B(t+2) [4] into Bc (fb fully read); A mt2/mt3; MFMA
        if (doB) {
#pragma unroll
            for (int s = 0; s < 4; ++s)
                stage16(gBs + (size_t)(s * 64) * K + kB, Bc + s * 4096 + wid * 512);
        }
        {
            half8 a00 = ldA(Ac, 2, 0), a01 = ldA(Ac, 2, 1);
            half8 a10 = ldA(Ac, 3, 0), a11 = ldA(Ac, 3, 1);
            __builtin_amdgcn_s_barrier();
            __builtin_amdgcn_s_setprio(1);
#pragma unroll
            for (int nt = 0; nt < 4; ++nt) {
                acc[2][nt] = __builtin_amdgcn_mfma_f32_16x16x32_f16(a00, fb[nt][0], acc[2][nt], 0, 0, 0);
                acc[2][nt] = __builtin_amdgcn_mfma_f32_16x16x32_f16(a01, fb[nt][1], acc[2][nt], 0, 0, 0);
                acc[3][nt] = __builtin_amdgcn_mfma_f32_16x16x32_f16(a10, fb[nt][0], acc[3][nt], 0, 0, 0);
                acc[3][nt] = __builtin_amdgcn_mfma_f32_16x16x32_f16(a11, fb[nt][1], acc[3][nt], 0, 0, 0);
            }
            __builtin_amdgcn_s_setprio(0);
        }
        // ---- tile end: counted vmcnt
        if (doB) {
            asm volatile("s_waitcnt vmcnt(4)" ::: "memory");
        } else if (doA) {
            asm volatile("s_waitcnt vmcnt(0)" ::: "memory");
        }
        __builtin_amdgcn_s_barrier();
        __builtin_amdgcn_sched_barrier(0);
    };

    for (int tt = 0; tt < NTk; tt += 2) {
        tile_body(tt, A0, B0, A1);
        if (tt + 1 < NTk)
            tile_body(tt + 1, A1, B1, A0);
    }

    // ---- epilogue: f32 direct coalesced-per-quad stores ----
#pragma unroll
    for (int mt = 0; mt < 4; ++mt)
#pragma unroll
        for (int nt = 0; nt < 4; ++nt)
#pragma unroll
            for (int r = 0; r < 4; ++r) {
                const size_t row = m0 + warpM + mt * 16 + quad * 4 + r;
                const size_t col = n0 + wn + nt * 16 + l16;
                Cout[row * (size_t)N + col] = acc[mt][nt][r];
            }
}

// ---------------------------------------------------------------------------
// MFMA flash attention v6: Q-tile 128, Bc=64, DOUBLE-BUFFERED K/V LDS.
// vs v5: 1 barrier per k-tile (was 2); LDS writes of tile t+1 target the idle
// buffer and overlap tile t's compute; T14 global loads for t+2 issued right
// after the writes -> a full tile of latency cover.
// LDS: 2 x (Kl 8KB + Vt 8KB) + Lstat = 33 KB; VGPR ~100 -> >=2 blocks/CU.
// ---------------------------------------------------------------------------
#define SCALE_EXP2 0.18033688f   // 0.125 * log2(e)

__global__ __launch_bounds__(256, 2) void attn_mfma(const half_t* __restrict__ qkv,
                                                    half_t* __restrict__ y) {
    __shared__ __align__(16) half_t Kl[2][64 * 64];
    __shared__ __align__(16) half_t Vt[2][64 * 64];
    __shared__ float Lstat[128];

    const int tid  = threadIdx.x;
    const int wid  = tid >> 6;
    const int lane = tid & 63;
    const int l16  = lane & 15;
    const int quad = lane >> 4;

    const int L = blockIdx.x;
    const int g = L & 63;                 // (b,h) group -> fixed XCD (g % 8)
    const int s = L >> 6;                 // pair slot 0..7
    const int h = g & 15;
    const int b = g >> 4;

    const size_t rs = 3 * C_EMB;
    const half_t* qb = qkv + (size_t)b * T_SEQ * rs + h * HS;
    const half_t* kb = qb + C_EMB;
    const half_t* vb = qb + 2 * C_EMB;

    const int srow = tid >> 2;            // 0..63
    const int scol = (tid & 3) * 16;      // 0,16,32,48 (halfs, global)
    const int sc2  = (tid & 3) * 2;       // LDS chunk pair base (16B chunks)
    const int rp   = tid & 31;            // row pair: rows 2rp, 2rp+1
    const int dblk = tid >> 5;            // 0..7 -> d = dblk*8 .. +8

    const int wq = wid * 32;              // wave's 32-q base within 128 tile

    // swizzled addressing: 16B chunk c of row r lives at chunk c^(r&7)
    auto kswz = [&](int bf, int row, int chunk) -> half_t* {
        return Kl[bf] + row * 64 + ((chunk ^ (row & 7)) << 3);
    };
    auto vswz = [&](int bf, int row, int chunk) -> half_t* {
        return Vt[bf] + row * 64 + ((chunk ^ (row & 7)) << 3);
    };

#pragma unroll 1
    for (int j = 0; j < 2; ++j) {
        const int jj = (j == 0) ? (15 - s) : s;   // 128-row job index 0..15
        const int q0 = jj * 128;
        const int ntk = 2 * jj + 2;               // k-tiles 0..2jj+1

        // ---- Q direct global -> regs (two 16-row subsets per wave) ----
        half8 aQ[2][2];
#pragma unroll
        for (int qs = 0; qs < 2; ++qs)
#pragma unroll
            for (int s2 = 0; s2 < 2; ++s2)
                aQ[qs][s2] = *(const half8*)(qb +
                    (size_t)(q0 + wq + qs * 16 + l16) * rs + s2 * 32 + quad * 8);

        // ---- prefetch k-tile 0 K/V into regs ----
        const half_t* kptr = kb + (size_t)srow * rs + scol;
        const half_t* vptr = vb + (size_t)(2 * rp) * rs + dblk * 8;
        half8 kp0, kp1;
        uint4 vpa, vpc;
        kp0 = *(const half8*)(kptr);
        kp1 = *(const half8*)(kptr + 8);
        vpa = *(const uint4*)(vptr);
        vpc = *(const uint4*)(vptr + rs);

        // LDS-write helpers (write regs -> buffer bf)
        auto writeK = [&](int bf) {
            *(half8*)kswz(bf, srow, sc2)     = kp0;
            *(half8*)kswz(bf, srow, sc2 + 1) = kp1;
        };
        auto writeV = [&](int bf) {
            const uint32_t a0[4] = {vpa.x, vpa.y, vpa.z, vpa.w};
            const uint32_t c0[4] = {vpc.x, vpc.y, vpc.z, vpc.w};
#pragma unroll
            for (int u = 0; u < 4; ++u) {
                const int d0 = dblk * 8 + 2 * u;
                const uint32_t w0 = (a0[u] & 0xffffu) | (c0[u] << 16);
                const uint32_t w1 = (a0[u] >> 16) | (c0[u] & 0xffff0000u);
                *(uint32_t*)((unsigned short*)vswz(bf, d0,     rp >> 2) + (rp & 3) * 2) = w0;
                *(uint32_t*)((unsigned short*)vswz(bf, d0 + 1, rp >> 2) + (rp & 3) * 2) = w1;
            }
        };

        // ---- prologue: tile0 -> buf0; issue tile1 loads; barrier ----
        __syncthreads();   // prior job's LDS reads done
        writeK(0);
        writeV(0);
        if (ntk > 1) {
            kptr += 64 * rs;
            vptr += 64 * rs;
            kp0 = *(const half8*)(kptr);
            kp1 = *(const half8*)(kptr + 8);
            vpa = *(const uint4*)(vptr);
            vpc = *(const uint4*)(vptr + rs);
        }
        __syncthreads();

        f32x4 O[2][4];
#pragma unroll
        for (int qs = 0; qs < 2; ++qs)
#pragma unroll
            for (int dt = 0; dt < 4; ++dt) O[qs][dt] = (f32x4){0.f, 0.f, 0.f, 0.f};
        float lw[2] = {0.f, 0.f};

        int cur = 0;
        for (int kt = 0; kt < ntk; ++kt) {
            // ---- write tile kt+1 into idle buffer; issue loads for kt+2 ----
            if (kt + 1 < ntk) {
                writeK(cur ^ 1);
                writeV(cur ^ 1);
                if (kt + 2 < ntk) {
                    kptr += 64 * rs;
                    vptr += 64 * rs;
                    kp0 = *(const half8*)(kptr);
                    kp1 = *(const half8*)(kptr + 8);
                    vpa = *(const uint4*)(vptr);
                    vpc = *(const uint4*)(vptr + rs);
                }
            }

            const bool dmask = (kt >= ntk - 2);   // last two tiles may need mask

            // ---- fused: S^T MFMA -> exp2 -> P frag -> O += P@V, two q-subsets ----
#pragma unroll
            for (int mt = 0; mt < 4; ++mt) {
                const half8 aK0 = *(const half8*)kswz(cur, mt * 16 + l16, quad);
                const half8 aK1 = *(const half8*)kswz(cur, mt * 16 + l16, 4 + quad);
                half4 bV[4];
#pragma unroll
                for (int dt = 0; dt < 4; ++dt)
                    bV[dt] = *(const half4*)(vswz(cur, dt * 16 + l16, 2 * mt + (quad >> 1)) +
                                             (quad & 1) * 4);
                const int kbase = kt * 64 + mt * 16 + quad * 4;   // global k of p[0]
#pragma unroll
                for (int qs = 0; qs < 2; ++qs) {
                    f32x4 sa = (f32x4){0.f, 0.f, 0.f, 0.f};
                    sa = __builtin_amdgcn_mfma_f32_16x16x32_f16(aK0, aQ[qs][0], sa, 0, 0, 0);
                    sa = __builtin_amdgcn_mfma_f32_16x16x32_f16(aK1, aQ[qs][1], sa, 0, 0, 0);

                    float p[4];
#pragma unroll
                    for (int r = 0; r < 4; ++r)
                        p[r] = __builtin_amdgcn_exp2f(sa[r] * SCALE_EXP2);
                    if (dmask) {
                        const int qg = q0 + wq + qs * 16 + l16;   // global q row
#pragma unroll
                        for (int r = 0; r < 4; ++r)
                            if (kbase + r > qg) p[r] = 0.f;
                    }
                    lw[qs] += (p[0] + p[1]) + (p[2] + p[3]);

                    const half4 pa = {(_Float16)p[0], (_Float16)p[1],
                                      (_Float16)p[2], (_Float16)p[3]};
#pragma unroll
                    for (int dt = 0; dt < 4; ++dt)
                        O[qs][dt] = mfma_k16(pa, bV[dt], O[qs][dt]);
                }
            }

            __syncthreads();   // writes of kt+1 visible; reads of kt done
            cur ^= 1;
        }

        // ---- epilogue: l-reduce, normalize, coalesced store via LDS (2 passes) ----
#pragma unroll
        for (int qs = 0; qs < 2; ++qs) {
            lw[qs] += __shfl_xor(lw[qs], 16);
            lw[qs] += __shfl_xor(lw[qs], 32);
            if (quad == 0) Lstat[wq + qs * 16 + l16] = lw[qs];
        }
        __syncthreads();   // loop-end barrier already passed; Lstat visible after this

        // pass A: q-rows 0..63 (waves 0,1) -> bounce through Vt[0]
        if (wid < 2) {
#pragma unroll
            for (int qs = 0; qs < 2; ++qs)
#pragma unroll
                for (int r = 0; r < 4; ++r) {
                    const int rowl = wq + qs * 16 + quad * 4 + r;   // 0..63
                    const float inv = 1.f / Lstat[rowl];
#pragma unroll
                    for (int dt = 0; dt < 4; ++dt)
                        *(vswz(0, rowl, 2 * dt + (l16 >> 3)) + (l16 & 7)) =
                            (half_t)(O[qs][dt][r] * inv);
                }
        }
        __syncthreads();
        {
            half_t* dst = y + ((size_t)b * T_SEQ + q0 + srow) * C_EMB + h * HS + scol;
            *(half8*)(dst)     = *(const half8*)vswz(0, srow, sc2);
            *(half8*)(dst + 8) = *(const half8*)vswz(0, srow, sc2 + 1);
        }
        __syncthreads();

        // pass B: q-rows 64..127 (waves 2,3) -> bounce through Vt[0]
        if (wid >= 2) {
#pragma unroll
            for (int qs = 0; qs < 2; ++qs)
#pragma unroll
                for (int r = 0; r < 4; ++r) {
                    const int rowg = wq + qs * 16 + quad * 4 + r;   // 64..127
                    const float inv = 1.f / Lstat[rowg];
#pragma unroll
                    for (int dt = 0; dt < 4; ++dt)
                        *(vswz(0, rowg - 64, 2 * dt + (l16 >> 3)) + (l16 & 7)) =
                            (half_t)(O[qs][dt][r] * inv);
                }
        }
        __syncthreads();
        {
            half_t* dst = y + ((size_t)b * T_SEQ + q0 + 64 + srow) * C_EMB + h * HS + scol;
            *(half8*)(dst)     = *(const half8*)vswz(0, srow, sc2);
            *(half8*)(dst + 8) = *(const half8*)vswz(0, srow, sc2 + 1);
        }
    }
}

// ---------------------------------------------------------------------------
extern "C" void kernel_launch(void* const* d_in, const int* in_sizes, int n_in,
                              void* d_out, int out_size, void* d_ws, size_t ws_size,
                              hipStream_t stream) {
    const float* x      = (const float*)d_in[0];   // [8192,1024]
    const float* w_attn = (const float*)d_in[1];   // [1024,3072]
    const float* w_proj = (const float*)d_in[2];   // [1024,1024]
    float* out = (float*)d_out;

    half_t* xh   = (half_t*)d_ws;                        // 16 MB
    half_t* waT  = xh   + (size_t)8192 * 1024;           //  6 MB [3072][1024]
    half_t* wpT  = waT  + (size_t)3072 * 1024;           //  2 MB [1024][1024]
    half_t* qkvh = wpT  + (size_t)1024 * 1024;           // 48 MB [8192][3072]
    half_t* yh   = qkvh + (size_t)8192 * 3072;           // 16 MB [8192][1024]

    // merged prep: x convert + both weight transposes
    prep_kernel<<<5120, 256, 0, stream>>>(x, xh, w_attn, waT, w_proj, wpT);

    // qkv = x @ w_attn   (256x256 template — proven 74.6 us)
    gemm256<<<dim3(384), 512, 0, stream>>>(xh, waT, qkvh, 8192, 3072, 1024);

    // attention v6 (512 balanced 128-q blocks, dbuf K/V, 1 barrier/tile)
    attn_mfma<<<dim3(512), 256, 0, stream>>>(qkvh, yh);

    // out = y @ w_proj   (128x256 template, 256 blocks = 1 full round, f32 out)
    gemm128f<<<dim3(256), 512, 0, stream>>>(yh, wpT, out, 8192, 1024, 1024);
}

// Round 9
// 241.282 us; speedup vs baseline: 2.9893x; 1.0578x over previous
//
#include <hip/hip_runtime.h>
#include <math.h>
#include <stdint.h>

#define B_BATCH 4
#define T_SEQ   2048
#define C_EMB   1024
#define NH      16
#define HS      64

#define SCALE_EXP2 0.18033688f   // 0.125 * log2(e), folded into waT Q-columns

typedef _Float16 half_t;
typedef __attribute__((ext_vector_type(8))) _Float16 half8;   // 4 VGPRs, 16 B
typedef __attribute__((ext_vector_type(4))) _Float16 half4;   // 2 VGPRs, 8 B
typedef __attribute__((ext_vector_type(2))) __fp16 pk16x2;    // cvt_pkrtz result type
typedef __attribute__((ext_vector_type(4))) float f32x4;

// K=16 f16 MFMA; fallback = zero-padded K=32 (A/B agree on slot map -> same dot)
static __device__ __forceinline__ f32x4 mfma_k16(half4 a, half4 b, f32x4 c) {
#if __has_builtin(__builtin_amdgcn_mfma_f32_16x16x16f16)
    return __builtin_amdgcn_mfma_f32_16x16x16f16(a, b, c, 0, 0, 0);
#else
    half8 a8 = {a.x, a.y, a.z, a.w, (_Float16)0, (_Float16)0, (_Float16)0, (_Float16)0};
    half8 b8 = {b.x, b.y, b.z, b.w, (_Float16)0, (_Float16)0, (_Float16)0, (_Float16)0};
    return __builtin_amdgcn_mfma_f32_16x16x32_f16(a8, b8, c, 0, 0, 0);
#endif
}

// async global->LDS, 16B/lane; LDS dest = wave-uniform base + lane*16
static __device__ __forceinline__ void stage16(const void* g, void* lds_base) {
#if __has_builtin(__builtin_amdgcn_global_load_lds)
    __builtin_amdgcn_global_load_lds(
        (const __attribute__((address_space(1))) void*)g,
        (__attribute__((address_space(3))) void*)lds_base, 16, 0, 0);
#else
    const int lane = threadIdx.x & 63;
    ((uint4*)lds_base)[lane] = *(const uint4*)g;
#endif
}

// ---------------------------------------------------------------------------
// Merged prep: fp32->f16 convert of x  +  both weight transposes.
// NEW: waT rows < 1024 (the Q output columns) are pre-scaled by SCALE_EXP2
// in f32 before the f16 convert — removes the per-element softmax scale
// multiply from attn's inner loop (linearity: K·(cQ) = c(K·Q)).
// ---------------------------------------------------------------------------
__global__ __launch_bounds__(256) void prep_kernel(const float* __restrict__ x,
                                                   half_t* __restrict__ xh,
                                                   const float* __restrict__ wa,
                                                   half_t* __restrict__ waT,
                                                   const float* __restrict__ wp,
                                                   half_t* __restrict__ wpT) {
    const int blk = blockIdx.x;
    const int tid = threadIdx.x;

    if (blk < 4096) {   // x convert: 8 elems/thread
        const int i = blk * 256 + tid;
        const float4 a = *(const float4*)(x + (size_t)i * 8);
        const float4 b = *(const float4*)(x + (size_t)i * 8 + 4);
        const pk16x2 h0 = __builtin_amdgcn_cvt_pkrtz(a.x, a.y);
        const pk16x2 h1 = __builtin_amdgcn_cvt_pkrtz(a.z, a.w);
        const pk16x2 h2 = __builtin_amdgcn_cvt_pkrtz(b.x, b.y);
        const pk16x2 h3 = __builtin_amdgcn_cvt_pkrtz(b.z, b.w);
        half8 o = {(_Float16)h0.x, (_Float16)h0.y, (_Float16)h1.x, (_Float16)h1.y,
                   (_Float16)h2.x, (_Float16)h2.y, (_Float16)h3.x, (_Float16)h3.y};
        *(half8*)(xh + (size_t)i * 8) = o;
        return;
    }

    // weight transpose: W[K][N] f32 -> WT[N][K] f16, 64x64 tile
    const float* W;
    half_t* WT;
    int K, N, bb;
    bool isQ;   // block is in w_attn's Q-column range?
    if (blk < 4096 + 768) {
        bb = blk - 4096; W = wa; WT = waT; K = 1024; N = 3072;
    } else {
        bb = blk - 4864; W = wp; WT = wpT; K = 1024; N = 1024;
    }
    const int ntiles = N / 64;
    const int n0 = (bb % ntiles) * 64;
    const int k0 = (bb / ntiles) * 64;
    isQ = (W == wa) && (n0 < 1024);   // whole 64-col tile is within Q range
    const float sc = isQ ? SCALE_EXP2 : 1.0f;

    __shared__ float t[64][65];
    const int r = tid >> 4, c4 = (tid & 15) * 4;
#pragma unroll
    for (int p = 0; p < 4; ++p) {
        const float4 g = *(const float4*)(W + (size_t)(k0 + p * 16 + r) * N + n0 + c4);
        t[p * 16 + r][c4 + 0] = g.x;
        t[p * 16 + r][c4 + 1] = g.y;
        t[p * 16 + r][c4 + 2] = g.z;
        t[p * 16 + r][c4 + 3] = g.w;
    }
    __syncthreads();
#pragma unroll
    for (int p = 0; p < 4; ++p) {
        const int n = p * 16 + r;
        half4 s = {(_Float16)(t[c4 + 0][n] * sc), (_Float16)(t[c4 + 1][n] * sc),
                   (_Float16)(t[c4 + 2][n] * sc), (_Float16)(t[c4 + 3][n] * sc)};
        *(half4*)(WT + (size_t)(n0 + n) * K + k0 + c4) = s;
    }
}

// ---------------------------------------------------------------------------
// 256x256 multi-phase f16 MFMA GEMM — PROVEN 74.6-75.4 us for QKV shape.
// launch_bounds(512,2): 256-reg cap, acc stays in AGPRs (VGPR_Count 120).
// ---------------------------------------------------------------------------
#define BK2 64

__global__ __launch_bounds__(512, 2) void gemm256(const half_t* __restrict__ A,
                                                  const half_t* __restrict__ Bt,
                                                  half_t* __restrict__ Cout,
                                                  int M, int N, int K) {
    // buf0: A [0,16384), B [16384,32768); buf1: A [32768,49152), B [49152,65536)
    __shared__ __align__(16) half_t SM[65536];   // 128 KiB

    const int tid  = threadIdx.x;
    const int lane = tid & 63;
    const int wid  = tid >> 6;
    const int l16  = lane & 15;
    const int quad = lane >> 4;

    // bijective XCD swizzle (gridDim.x % 8 == 0)
    const int nwg = gridDim.x;
    const int cpx = nwg >> 3;
    const int bid = (blockIdx.x & 7) * cpx + (blockIdx.x >> 3);
    const int nbx = N >> 8;
    const int bx = bid % nbx;
    const int by = bid / nbx;
    const size_t m0 = (size_t)by << 8;
    const size_t n0 = (size_t)bx << 8;

    const int warpM = (wid >> 2) * 128;   // wave's M half
    const int wn    = (wid & 3) * 64;     // wave's 64-col N slice
    const int NTk   = K >> 6;

    // staging: thread t covers row (tid>>3), swizzled chunk (tid&7)^((tid>>3)&7)
    const int srow = tid >> 3;
    const int scsw = (tid & 7) ^ (srow & 7);
    const half_t* gAs = A  + (m0 + srow) * (size_t)K + scsw * 8;
    const half_t* gBs = Bt + (n0 + srow) * (size_t)K + scsw * 8;

    f32x4 acc[8][4];
#pragma unroll
    for (int i = 0; i < 8; ++i)
#pragma unroll
        for (int j = 0; j < 4; ++j) acc[i][j] = (f32x4){0.f, 0.f, 0.f, 0.f};

    // swizzled fragment loads (r&7 == l16&7 since all row bases are %8==0)
    auto ldA = [&](const half_t* Ab, int mt, int kk) -> half8 {
        const int r = warpM + mt * 16 + l16;
        const int c = (kk * 4 + quad) ^ (l16 & 7);
        return *(const half8*)(Ab + r * 64 + c * 8);
    };
    auto ldB = [&](const half_t* Bb, int nt, int kk) -> half8 {
        const int r = wn + nt * 16 + l16;
        const int c = (kk * 4 + quad) ^ (l16 & 7);
        return *(const half8*)(Bb + r * 64 + c * 8);
    };

    // ---- prologue: tile0 (A+B)->buf0, tile1 B->buf1; vmcnt(4) keeps tile1-B in flight
#pragma unroll
    for (int s = 0; s < 4; ++s)
        stage16(gAs + (size_t)(s * 64) * K, SM + s * 4096 + wid * 512);
#pragma unroll
    for (int s = 0; s < 4; ++s)
        stage16(gBs + (size_t)(s * 64) * K, SM + 16384 + s * 4096 + wid * 512);
    if (NTk > 1) {
#pragma unroll
        for (int s = 0; s < 4; ++s)
            stage16(gBs + (size_t)(s * 64) * K + BK2, SM + 49152 + s * 4096 + wid * 512);
        asm volatile("s_waitcnt vmcnt(4)" ::: "memory");
    } else {
        asm volatile("s_waitcnt vmcnt(0)" ::: "memory");
    }
    __builtin_amdgcn_s_barrier();
    __builtin_amdgcn_sched_barrier(0);

    auto tile_body = [&](int t, half_t* Ac, half_t* Bc, half_t* An) {
        const int kA = (t + 1) * BK2;
        const int kB = (t + 2) * BK2;
        const bool doA = (t + 1) < NTk;
        const bool doB = (t + 2) < NTk;

        half8 fb[4][2];

        // ---- phase 0: stage A-half0(t+1); read B-frags + A quad0; MFMA q0
        if (doA) {
            stage16(gAs + (size_t)(0 * 64) * K + kA, An + 0 * 4096 + wid * 512);
            stage16(gAs + (size_t)(1 * 64) * K + kA, An + 1 * 4096 + wid * 512);
        }
#pragma unroll
        for (int nt = 0; nt < 4; ++nt) {
            fb[nt][0] = ldB(Bc, nt, 0);
            fb[nt][1] = ldB(Bc, nt, 1);
        }
        {
            half8 a00 = ldA(Ac, 0, 0), a01 = ldA(Ac, 0, 1);
            half8 a10 = ldA(Ac, 1, 0), a11 = ldA(Ac, 1, 1);
            __builtin_amdgcn_s_barrier();
            __builtin_amdgcn_s_setprio(1);
#pragma unroll
            for (int nt = 0; nt < 4; ++nt) {
                acc[0][nt] = __builtin_amdgcn_mfma_f32_16x16x32_f16(a00, fb[nt][0], acc[0][nt], 0, 0, 0);
                acc[0][nt] = __builtin_amdgcn_mfma_f32_16x16x32_f16(a01, fb[nt][1], acc[0][nt], 0, 0, 0);
                acc[1][nt] = __builtin_amdgcn_mfma_f32_16x16x32_f16(a10, fb[nt][0], acc[1][nt], 0, 0, 0);
                acc[1][nt] = __builtin_amdgcn_mfma_f32_16x16x32_f16(a11, fb[nt][1], acc[1][nt], 0, 0, 0);
            }
            __builtin_amdgcn_s_setprio(0);
        }
        // ---- phase 1: stage A-half1(t+1); A quad1; MFMA q1
        if (doA) {
            stage16(gAs + (size_t)(2 * 64) * K + kA, An + 2 * 4096 + wid * 512);
            stage16(gAs + (size_t)(3 * 64) * K + kA, An + 3 * 4096 + wid * 512);
        }
        {
            half8 a00 = ldA(Ac, 2, 0), a01 = ldA(Ac, 2, 1);
            half8 a10 = ldA(Ac, 3, 0), a11 = ldA(Ac, 3, 1);
            __builtin_amdgcn_s_barrier();
            __builtin_amdgcn_s_setprio(1);
#pragma unroll
            for (int nt = 0; nt < 4; ++nt) {
                acc[2][nt] = __builtin_amdgcn_mfma_f32_16x16x32_f16(a00, fb[nt][0], acc[2][nt], 0, 0, 0);
                acc[2][nt] = __builtin_amdgcn_mfma_f32_16x16x32_f16(a01, fb[nt][1], acc[2][nt], 0, 0, 0);
                acc[3][nt] = __builtin_amdgcn_mfma_f32_16x16x32_f16(a10, fb[nt][0], acc[3][nt], 0, 0, 0);
                acc[3][nt] = __builtin_amdgcn_mfma_f32_16x16x32_f16(a11, fb[nt][1], acc[3][nt], 0, 0, 0);
            }
            __builtin_amdgcn_s_setprio(0);
        }
        // ---- phase 2: stage B-half0(t+2) into Bc; MFMA q2
        if (doB) {
            stage16(gBs + (size_t)(0 * 64) * K + kB, Bc + 0 * 4096 + wid * 512);
            stage16(gBs + (size_t)(1 * 64) * K + kB, Bc + 1 * 4096 + wid * 512);
        }
        {
            half8 a00 = ldA(Ac, 4, 0), a01 = ldA(Ac, 4, 1);
            half8 a10 = ldA(Ac, 5, 0), a11 = ldA(Ac, 5, 1);
            __builtin_amdgcn_s_barrier();
            __builtin_amdgcn_s_setprio(1);
#pragma unroll
            for (int nt = 0; nt < 4; ++nt) {
                acc[4][nt] = __builtin_amdgcn_mfma_f32_16x16x32_f16(a00, fb[nt][0], acc[4][nt], 0, 0, 0);
                acc[4][nt] = __builtin_amdgcn_mfma_f32_16x16x32_f16(a01, fb[nt][1], acc[4][nt], 0, 0, 0);
                acc[5][nt] = __builtin_amdgcn_mfma_f32_16x16x32_f16(a10, fb[nt][0], acc[5][nt], 0, 0, 0);
                acc[5][nt] = __builtin_amdgcn_mfma_f32_16x16x32_f16(a11, fb[nt][1], acc[5][nt], 0, 0, 0);
            }
            __builtin_amdgcn_s_setprio(0);
        }
        // ---- phase 3: stage B-half1(t+2); MFMA q3
        if (doB) {
            stage16(gBs + (size_t)(2 * 64) * K + kB, Bc + 2 * 4096 + wid * 512);
            stage16(gBs + (size_t)(3 * 64) * K + kB, Bc + 3 * 4096 + wid * 512);
        }
        {
            half8 a00 = ldA(Ac, 6, 0), a01 = ldA(Ac, 6, 1);
            half8 a10 = ldA(Ac, 7, 0), a11 = ldA(Ac, 7, 1);
            __builtin_amdgcn_s_barrier();
            __builtin_amdgcn_s_setprio(1);
#pragma unroll
            for (int nt = 0; nt < 4; ++nt) {
                acc[6][nt] = __builtin_amdgcn_mfma_f32_16x16x32_f16(a00, fb[nt][0], acc[6][nt], 0, 0, 0);
                acc[6][nt] = __builtin_amdgcn_mfma_f32_16x16x32_f16(a01, fb[nt][1], acc[6][nt], 0, 0, 0);
                acc[7][nt] = __builtin_amdgcn_mfma_f32_16x16x32_f16(a10, fb[nt][0], acc[7][nt], 0, 0, 0);
                acc[7][nt] = __builtin_amdgcn_mfma_f32_16x16x32_f16(a11, fb[nt][1], acc[7][nt], 0, 0, 0);
            }
            __builtin_amdgcn_s_setprio(0);
        }
        // ---- tile end: counted vmcnt (retire A(t+1)+older; keep B(t+2) in flight)
        if (doB) {
            asm volatile("s_waitcnt vmcnt(4)" ::: "memory");
        } else if (doA) {
            asm volatile("s_waitcnt vmcnt(0)" ::: "memory");
        }
        __builtin_amdgcn_s_barrier();
        __builtin_amdgcn_sched_barrier(0);
    };

    for (int tt = 0; tt < NTk; tt += 2) {
        tile_body(tt, SM, SM + 16384, SM + 32768);
        if (tt + 1 < NTk)
            tile_body(tt + 1, SM + 32768, SM + 49152, SM);
    }

    // ---- epilogue: coalesced f16 stores via per-wave LDS transpose bounce ----
    __syncthreads();
    float* cw = (float*)SM + wid * 1024;   // 4 KB/wave scratch
    const int rrow = lane >> 2;            // 0..15
    const int cseg = (lane & 3) * 16;      // 0,16,32,48
#pragma unroll
    for (int mt = 0; mt < 8; ++mt) {
#pragma unroll
        for (int nt = 0; nt < 4; ++nt)
            *(f32x4*)&cw[(nt * 16 + l16) * 16 + quad * 4] = acc[mt][nt];
        // wave-internal LDS dep: DS ops are processed in order per wave
        half_t tmp[16];
#pragma unroll
        for (int jj = 0; jj < 16; ++jj)
            tmp[jj] = (half_t)cw[(cseg + jj) * 16 + rrow];
        half_t* dst = Cout + (m0 + warpM + mt * 16 + rrow) * (size_t)N + n0 + wn + cseg;
        *(half8*)(dst)     = *(const half8*)(tmp);
        *(half8*)(dst + 8) = *(const half8*)(tmp + 8);
    }
}

// ---------------------------------------------------------------------------
// 128x256 multi-phase f16 MFMA GEMM (for proj: 256 blocks = 1 full round).
// f32 out. Proven structure, unchanged.
// ---------------------------------------------------------------------------
__global__ __launch_bounds__(512, 2) void gemm128f(const half_t* __restrict__ A,
                                                   const half_t* __restrict__ Bt,
                                                   float* __restrict__ Cout,
                                                   int M, int N, int K) {
    // halfs: A0 [0,8192) B0 [8192,24576) A1 [24576,32768) B1 [32768,49152)
    __shared__ __align__(16) half_t SM[49152];   // 96 KiB

    const int tid  = threadIdx.x;
    const int lane = tid & 63;
    const int wid  = tid >> 6;
    const int l16  = lane & 15;
    const int quad = lane >> 4;

    // bijective XCD swizzle (gridDim.x % 8 == 0)
    const int nwg = gridDim.x;
    const int cpx = nwg >> 3;
    const int bid = (blockIdx.x & 7) * cpx + (blockIdx.x >> 3);
    const int nbx = N >> 8;                 // 256-col tiles
    const int bx = bid % nbx;
    const int by = bid / nbx;
    const size_t m0 = (size_t)by << 7;      // 128-row tiles
    const size_t n0 = (size_t)bx << 8;

    const int warpM = (wid >> 2) * 64;      // wave's M half (64 rows)
    const int wn    = (wid & 3) * 64;       // wave's 64-col N slice
    const int NTk   = K >> 6;

    const int srow = tid >> 3;
    const int scsw = (tid & 7) ^ (srow & 7);
    const half_t* gAs = A  + (m0 + srow) * (size_t)K + scsw * 8;
    const half_t* gBs = Bt + (n0 + srow) * (size_t)K + scsw * 8;

    half_t* const A0 = SM;
    half_t* const B0 = SM + 8192;
    half_t* const A1 = SM + 24576;
    half_t* const B1 = SM + 32768;

    f32x4 acc[4][4];
#pragma unroll
    for (int i = 0; i < 4; ++i)
#pragma unroll
        for (int j = 0; j < 4; ++j) acc[i][j] = (f32x4){0.f, 0.f, 0.f, 0.f};

    auto ldA = [&](const half_t* Ab, int mt, int kk) -> half8 {
        const int r = warpM + mt * 16 + l16;
        const int c = (kk * 4 + quad) ^ (l16 & 7);
        return *(const half8*)(Ab + r * 64 + c * 8);
    };
    auto ldB = [&](const half_t* Bb, int nt, int kk) -> half8 {
        const int r = wn + nt * 16 + l16;
        const int c = (kk * 4 + quad) ^ (l16 & 7);
        return *(const half8*)(Bb + r * 64 + c * 8);
    };

    // ---- prologue: tile0 A(2)+B(4)->buf0, tile1 B(4)->buf1; vmcnt(4)
#pragma unroll
    for (int s = 0; s < 2; ++s)
        stage16(gAs + (size_t)(s * 64) * K, A0 + s * 4096 + wid * 512);
#pragma unroll
    for (int s = 0; s < 4; ++s)
        stage16(gBs + (size_t)(s * 64) * K, B0 + s * 4096 + wid * 512);
    if (NTk > 1) {
#pragma unroll
        for (int s = 0; s < 4; ++s)
            stage16(gBs + (size_t)(s * 64) * K + BK2, B1 + s * 4096 + wid * 512);
        asm volatile("s_waitcnt vmcnt(4)" ::: "memory");
    } else {
        asm volatile("s_waitcnt vmcnt(0)" ::: "memory");
    }
    __builtin_amdgcn_s_barrier();
    __builtin_amdgcn_sched_barrier(0);

    auto tile_body = [&](int t, half_t* Ac, half_t* Bc, half_t* An) {
        const int kA = (t + 1) * BK2;
        const int kB = (t + 2) * BK2;
        const bool doA = (t + 1) < NTk;
        const bool doB = (t + 2) < NTk;

        half8 fb[4][2];

        // ---- phase A: stage A(t+1) [2]; read ALL B-frags + A mt0/mt1; MFMA
        if (doA) {
            stage16(gAs + (size_t)(0 * 64) * K + kA, An + 0 * 4096 + wid * 512);
            stage16(gAs + (size_t)(1 * 64) * K + kA, An + 1 * 4096 + wid * 512);
        }
#pragma unroll
        for (int nt = 0; nt < 4; ++nt) {
            fb[nt][0] = ldB(Bc, nt, 0);
            fb[nt][1] = ldB(Bc, nt, 1);
        }
        {
            half8 a00 = ldA(Ac, 0, 0), a01 = ldA(Ac, 0, 1);
            half8 a10 = ldA(Ac, 1, 0), a11 = ldA(Ac, 1, 1);
            __builtin_amdgcn_s_barrier();
            __builtin_amdgcn_s_setprio(1);
#pragma unroll
            for (int nt = 0; nt < 4; ++nt) {
                acc[0][nt] = __builtin_amdgcn_mfma_f32_16x16x32_f16(a00, fb[nt][0], acc[0][nt], 0, 0, 0);
                acc[0][nt] = __builtin_amdgcn_mfma_f32_16x16x32_f16(a01, fb[nt][1], acc[0][nt], 0, 0, 0);
                acc[1][nt] = __builtin_amdgcn_mfma_f32_16x16x32_f16(a10, fb[nt][0], acc[1][nt], 0, 0, 0);
                acc[1][nt] = __builtin_amdgcn_mfma_f32_16x16x32_f16(a11, fb[nt][1], acc[1][nt], 0, 0, 0);
            }
            __builtin_amdgcn_s_setprio(0);
        }
        // ---- phase B: stage B(t+2) [4] into Bc (fb fully read); A mt2/mt3; MFMA
        if (doB) {
#pragma unroll
            for (int s = 0; s < 4; ++s)
                stage16(gBs + (size_t)(s * 64) * K + kB, Bc + s * 4096 + wid * 512);
        }
        {
            half8 a00 = ldA(Ac, 2, 0), a01 = ldA(Ac, 2, 1);
            half8 a10 = ldA(Ac, 3, 0), a11 = ldA(Ac, 3, 1);
            __builtin_amdgcn_s_barrier();
            __builtin_amdgcn_s_setprio(1);
#pragma unroll
            for (int nt = 0; nt < 4; ++nt) {
                acc[2][nt] = __builtin_amdgcn_mfma_f32_16x16x32_f16(a00, fb[nt][0], acc[2][nt], 0, 0, 0);
                acc[2][nt] = __builtin_amdgcn_mfma_f32_16x16x32_f16(a01, fb[nt][1], acc[2][nt], 0, 0, 0);
                acc[3][nt] = __builtin_amdgcn_mfma_f32_16x16x32_f16(a10, fb[nt][0], acc[3][nt], 0, 0, 0);
                acc[3][nt] = __builtin_amdgcn_mfma_f32_16x16x32_f16(a11, fb[nt][1], acc[3][nt], 0, 0, 0);
            }
            __builtin_amdgcn_s_setprio(0);
        }
        // ---- tile end: counted vmcnt
        if (doB) {
            asm volatile("s_waitcnt vmcnt(4)" ::: "memory");
        } else if (doA) {
            asm volatile("s_waitcnt vmcnt(0)" ::: "memory");
        }
        __builtin_amdgcn_s_barrier();
        __builtin_amdgcn_sched_barrier(0);
    };

    for (int tt = 0; tt < NTk; tt += 2) {
        tile_body(tt, A0, B0, A1);
        if (tt + 1 < NTk)
            tile_body(tt + 1, A1, B1, A0);
    }

    // ---- epilogue: f32 direct coalesced-per-quad stores ----
#pragma unroll
    for (int mt = 0; mt < 4; ++mt)
#pragma unroll
        for (int nt = 0; nt < 4; ++nt)
#pragma unroll
            for (int r = 0; r < 4; ++r) {
                const size_t row = m0 + warpM + mt * 16 + quad * 4 + r;
                const size_t col = n0 + wn + nt * 16 + l16;
                Cout[row * (size_t)N + col] = acc[mt][nt][r];
            }
}

// ---------------------------------------------------------------------------
// MFMA flash attention v5 (proven): Q-tile 128 (4 waves x 32 q-rows), Bc=64,
// single-buffer XOR-swizzled LDS, T14 reg-prefetch.
// NEW: Q arrives pre-scaled by SCALE_EXP2 (folded into waT in prep) ->
// p = exp2(sa) directly, no per-element multiply.
// ---------------------------------------------------------------------------
__global__ __launch_bounds__(256, 2) void attn_mfma(const half_t* __restrict__ qkv,
                                                    half_t* __restrict__ y) {
    __shared__ __align__(16) half_t Kl[64 * 64];
    __shared__ __align__(16) half_t Vt[64 * 64];
    __shared__ float Lstat[128];

    const int tid  = threadIdx.x;
    const int wid  = tid >> 6;
    const int lane = tid & 63;
    const int l16  = lane & 15;
    const int quad = lane >> 4;

    const int L = blockIdx.x;
    const int g = L & 63;                 // (b,h) group -> fixed XCD (g % 8)
    const int s = L >> 6;                 // pair slot 0..7
    const int h = g & 15;
    const int b = g >> 4;

    const size_t rs = 3 * C_EMB;
    const half_t* qb = qkv + (size_t)b * T_SEQ * rs + h * HS;
    const half_t* kb = qb + C_EMB;
    const half_t* vb = qb + 2 * C_EMB;

    const int srow = tid >> 2;            // 0..63
    const int scol = (tid & 3) * 16;      // 0,16,32,48 (halfs, global)
    const int sc2  = (tid & 3) * 2;       // LDS chunk pair base (16B chunks)
    const int rp   = tid & 31;            // row pair: rows 2rp, 2rp+1
    const int dblk = tid >> 5;            // 0..7 -> d = dblk*8 .. +8

    const int wq = wid * 32;              // wave's 32-q base within 128 tile

    // swizzled addressing: 16B chunk c of row r lives at chunk c^(r&7)
    auto kswz = [&](int row, int chunk) -> half_t* {
        return Kl + row * 64 + ((chunk ^ (row & 7)) << 3);
    };
    auto vswz = [&](int row, int chunk) -> half_t* {
        return Vt + row * 64 + ((chunk ^ (row & 7)) << 3);
    };

#pragma unroll 1
    for (int j = 0; j < 2; ++j) {
        const int jj = (j == 0) ? (15 - s) : s;   // 128-row job index 0..15
        const int q0 = jj * 128;
        const int ntk = 2 * jj + 2;               // k-tiles 0..2jj+1

        // ---- Q direct global -> regs (two 16-row subsets per wave) ----
        half8 aQ[2][2];
#pragma unroll
        for (int qs = 0; qs < 2; ++qs)
#pragma unroll
            for (int s2 = 0; s2 < 2; ++s2)
                aQ[qs][s2] = *(const half8*)(qb +
                    (size_t)(q0 + wq + qs * 16 + l16) * rs + s2 * 32 + quad * 8);

        // ---- prefetch k-tile 0 K/V into regs ----
        const half_t* kptr = kb + (size_t)srow * rs + scol;
        const half_t* vptr = vb + (size_t)(2 * rp) * rs + dblk * 8;
        half8 kp0, kp1;
        uint4 vpa, vpc;
        kp0 = *(const half8*)(kptr);
        kp1 = *(const half8*)(kptr + 8);
        vpa = *(const uint4*)(vptr);
        vpc = *(const uint4*)(vptr + rs);

        f32x4 O[2][4];
#pragma unroll
        for (int qs = 0; qs < 2; ++qs)
#pragma unroll
            for (int dt = 0; dt < 4; ++dt) O[qs][dt] = (f32x4){0.f, 0.f, 0.f, 0.f};
        float lw[2] = {0.f, 0.f};

        for (int kt = 0; kt < ntk; ++kt) {
            __syncthreads();   // prior tile frag reads / prior epilogue reads done

            // ---- write prefetched K: Kl[kcol][d], swizzled ----
            *(half8*)kswz(srow, sc2)     = kp0;
            *(half8*)kswz(srow, sc2 + 1) = kp1;
            // ---- write prefetched V^T: Vt[d][kcol], paired-row b32 packing ----
            {
                const uint32_t a0[4] = {vpa.x, vpa.y, vpa.z, vpa.w};
                const uint32_t c0[4] = {vpc.x, vpc.y, vpc.z, vpc.w};
#pragma unroll
                for (int u = 0; u < 4; ++u) {
                    const int d0 = dblk * 8 + 2 * u;
                    const uint32_t w0 = (a0[u] & 0xffffu) | (c0[u] << 16);
                    const uint32_t w1 = (a0[u] >> 16) | (c0[u] & 0xffff0000u);
                    *(uint32_t*)((unsigned short*)vswz(d0,     rp >> 2) + (rp & 3) * 2) = w0;
                    *(uint32_t*)((unsigned short*)vswz(d0 + 1, rp >> 2) + (rp & 3) * 2) = w1;
                }
            }
            __syncthreads();

            // ---- T14: issue next tile's loads (increment-only addressing) ----
            if (kt + 1 < ntk) {
                kptr += 64 * rs;
                vptr += 64 * rs;
                kp0 = *(const half8*)(kptr);
                kp1 = *(const half8*)(kptr + 8);
                vpa = *(const uint4*)(vptr);
                vpc = *(const uint4*)(vptr + rs);
            }

            const bool dmask = (kt >= ntk - 2);   // last two tiles may need mask

            // ---- fused: S^T MFMA -> exp2 -> P frag -> O += P@V, two q-subsets ----
#pragma unroll
            for (int mt = 0; mt < 4; ++mt) {
                const half8 aK0 = *(const half8*)kswz(mt * 16 + l16, quad);
                const half8 aK1 = *(const half8*)kswz(mt * 16 + l16, 4 + quad);
                half4 bV[4];
#pragma unroll
                for (int dt = 0; dt < 4; ++dt)
                    bV[dt] = *(const half4*)(vswz(dt * 16 + l16, 2 * mt + (quad >> 1)) +
                                             (quad & 1) * 4);
                const int kbase = kt * 64 + mt * 16 + quad * 4;   // global k of p[0]
#pragma unroll
                for (int qs = 0; qs < 2; ++qs) {
                    f32x4 sa = (f32x4){0.f, 0.f, 0.f, 0.f};
                    sa = __builtin_amdgcn_mfma_f32_16x16x32_f16(aK0, aQ[qs][0], sa, 0, 0, 0);
                    sa = __builtin_amdgcn_mfma_f32_16x16x32_f16(aK1, aQ[qs][1], sa, 0, 0, 0);

                    float p[4];
#pragma unroll
                    for (int r = 0; r < 4; ++r)
                        p[r] = __builtin_amdgcn_exp2f(sa[r]);   // scale pre-folded into Q
                    if (dmask) {
                        const int qg = q0 + wq + qs * 16 + l16;   // global q row
#pragma unroll
                        for (int r = 0; r < 4; ++r)
                            if (kbase + r > qg) p[r] = 0.f;
                    }
                    lw[qs] += (p[0] + p[1]) + (p[2] + p[3]);

                    const half4 pa = {(_Float16)p[0], (_Float16)p[1],
                                      (_Float16)p[2], (_Float16)p[3]};
#pragma unroll
                    for (int dt = 0; dt < 4; ++dt)
                        O[qs][dt] = mfma_k16(pa, bV[dt], O[qs][dt]);
                }
            }
        }

        // ---- epilogue: l-reduce, normalize, coalesced store via LDS (2 passes) ----
#pragma unroll
        for (int qs = 0; qs < 2; ++qs) {
            lw[qs] += __shfl_xor(lw[qs], 16);
            lw[qs] += __shfl_xor(lw[qs], 32);
            if (quad == 0) Lstat[wq + qs * 16 + l16] = lw[qs];
        }
        __syncthreads();   // all waves done reading Vt/Kl; Lstat visible

        // pass A: q-rows 0..63 (waves 0,1)
        if (wid < 2) {
#pragma unroll
            for (int qs = 0; qs < 2; ++qs)
#pragma unroll
                for (int r = 0; r < 4; ++r) {
                    const int rowl = wq + qs * 16 + quad * 4 + r;   // 0..63
                    const float inv = 1.f / Lstat[rowl];
#pragma unroll
                    for (int dt = 0; dt < 4; ++dt)
                        *(vswz(rowl, 2 * dt + (l16 >> 3)) + (l16 & 7)) =
                            (half_t)(O[qs][dt][r] * inv);
                }
        }
        __syncthreads();
        {
            half_t* dst = y + ((size_t)b * T_SEQ + q0 + srow) * C_EMB + h * HS + scol;
            *(half8*)(dst)     = *(const half8*)vswz(srow, sc2);
            *(half8*)(dst + 8) = *(const half8*)vswz(srow, sc2 + 1);
        }
        __syncthreads();

        // pass B: q-rows 64..127 (waves 2,3)
        if (wid >= 2) {
#pragma unroll
            for (int qs = 0; qs < 2; ++qs)
#pragma unroll
                for (int r = 0; r < 4; ++r) {
                    const int rowg = wq + qs * 16 + quad * 4 + r;   // 64..127
                    const float inv = 1.f / Lstat[rowg];
#pragma unroll
                    for (int dt = 0; dt < 4; ++dt)
                        *(vswz(rowg - 64, 2 * dt + (l16 >> 3)) + (l16 & 7)) =
                            (half_t)(O[qs][dt][r] * inv);
                }
        }
        __syncthreads();
        {
            half_t* dst = y + ((size_t)b * T_SEQ + q0 + 64 + srow) * C_EMB + h * HS + scol;
            *(half8*)(dst)     = *(const half8*)vswz(srow, sc2);
            *(half8*)(dst + 8) = *(const half8*)vswz(srow, sc2 + 1);
        }
    }
}

// ---------------------------------------------------------------------------
extern "C" void kernel_launch(void* const* d_in, const int* in_sizes, int n_in,
                              void* d_out, int out_size, void* d_ws, size_t ws_size,
                              hipStream_t stream) {
    const float* x      = (const float*)d_in[0];   // [8192,1024]
    const float* w_attn = (const float*)d_in[1];   // [1024,3072]
    const float* w_proj = (const float*)d_in[2];   // [1024,1024]
    float* out = (float*)d_out;

    half_t* xh   = (half_t*)d_ws;                        // 16 MB
    half_t* waT  = xh   + (size_t)8192 * 1024;           //  6 MB [3072][1024]
    half_t* wpT  = waT  + (size_t)3072 * 1024;           //  2 MB [1024][1024]
    half_t* qkvh = wpT  + (size_t)1024 * 1024;           // 48 MB [8192][3072]
    half_t* yh   = qkvh + (size_t)8192 * 3072;           // 16 MB [8192][1024]

    // merged prep: x convert + both weight transposes (Q-cols pre-scaled)
    prep_kernel<<<5120, 256, 0, stream>>>(x, xh, w_attn, waT, w_proj, wpT);

    // qkv = x @ w_attn   (256x256 template — proven)
    gemm256<<<dim3(384), 512, 0, stream>>>(xh, waT, qkvh, 8192, 3072, 1024);

    // attention v5 (512 balanced 128-q blocks, XCD-swizzled) — proven
    attn_mfma<<<dim3(512), 256, 0, stream>>>(qkvh, yh);

    // out = y @ w_proj   (128x256 template, 256 blocks = 1 full round, f32 out)
    gemm128f<<<dim3(256), 512, 0, stream>>>(yh, wpT, out, 8192, 1024, 1024);
}

// Round 10
// 236.263 us; speedup vs baseline: 3.0528x; 1.0212x over previous
//
#include <hip/hip_runtime.h>
#include <math.h>
#include <stdint.h>

#define B_BATCH 4
#define T_SEQ   2048
#define C_EMB   1024
#define NH      16
#define HS      64

#define SCALE_EXP2 0.18033688f   // 0.125 * log2(e), folded into waT Q-columns

typedef _Float16 half_t;
typedef __attribute__((ext_vector_type(8))) _Float16 half8;   // 4 VGPRs, 16 B
typedef __attribute__((ext_vector_type(4))) _Float16 half4;   // 2 VGPRs, 8 B
typedef __attribute__((ext_vector_type(2))) __fp16 pk16x2;    // cvt_pkrtz result type
typedef __attribute__((ext_vector_type(4))) float f32x4;

// K=16 f16 MFMA; fallback = zero-padded K=32 (A/B agree on slot map -> same dot)
static __device__ __forceinline__ f32x4 mfma_k16(half4 a, half4 b, f32x4 c) {
#if __has_builtin(__builtin_amdgcn_mfma_f32_16x16x16f16)
    return __builtin_amdgcn_mfma_f32_16x16x16f16(a, b, c, 0, 0, 0);
#else
    half8 a8 = {a.x, a.y, a.z, a.w, (_Float16)0, (_Float16)0, (_Float16)0, (_Float16)0};
    half8 b8 = {b.x, b.y, b.z, b.w, (_Float16)0, (_Float16)0, (_Float16)0, (_Float16)0};
    return __builtin_amdgcn_mfma_f32_16x16x32_f16(a8, b8, c, 0, 0, 0);
#endif
}

// async global->LDS, 16B/lane; LDS dest = wave-uniform base + lane*16
static __device__ __forceinline__ void stage16(const void* g, void* lds_base) {
#if __has_builtin(__builtin_amdgcn_global_load_lds)
    __builtin_amdgcn_global_load_lds(
        (const __attribute__((address_space(1))) void*)g,
        (__attribute__((address_space(3))) void*)lds_base, 16, 0, 0);
#else
    const int lane = threadIdx.x & 63;
    ((uint4*)lds_base)[lane] = *(const uint4*)g;
#endif
}

// ---------------------------------------------------------------------------
// Merged prep: fp32->f16 convert of x  +  both weight transposes.
// waT rows < 1024 (Q output columns) pre-scaled by SCALE_EXP2 in f32 before
// the f16 convert (linearity: K·(cQ) = c(K·Q)).
// ---------------------------------------------------------------------------
__global__ __launch_bounds__(256) void prep_kernel(const float* __restrict__ x,
                                                   half_t* __restrict__ xh,
                                                   const float* __restrict__ wa,
                                                   half_t* __restrict__ waT,
                                                   const float* __restrict__ wp,
                                                   half_t* __restrict__ wpT) {
    const int blk = blockIdx.x;
    const int tid = threadIdx.x;

    if (blk < 4096) {   // x convert: 8 elems/thread
        const int i = blk * 256 + tid;
        const float4 a = *(const float4*)(x + (size_t)i * 8);
        const float4 b = *(const float4*)(x + (size_t)i * 8 + 4);
        const pk16x2 h0 = __builtin_amdgcn_cvt_pkrtz(a.x, a.y);
        const pk16x2 h1 = __builtin_amdgcn_cvt_pkrtz(a.z, a.w);
        const pk16x2 h2 = __builtin_amdgcn_cvt_pkrtz(b.x, b.y);
        const pk16x2 h3 = __builtin_amdgcn_cvt_pkrtz(b.z, b.w);
        half8 o = {(_Float16)h0.x, (_Float16)h0.y, (_Float16)h1.x, (_Float16)h1.y,
                   (_Float16)h2.x, (_Float16)h2.y, (_Float16)h3.x, (_Float16)h3.y};
        *(half8*)(xh + (size_t)i * 8) = o;
        return;
    }

    // weight transpose: W[K][N] f32 -> WT[N][K] f16, 64x64 tile
    const float* W;
    half_t* WT;
    int K, N, bb;
    bool isQ;
    if (blk < 4096 + 768) {
        bb = blk - 4096; W = wa; WT = waT; K = 1024; N = 3072;
    } else {
        bb = blk - 4864; W = wp; WT = wpT; K = 1024; N = 1024;
    }
    const int ntiles = N / 64;
    const int n0 = (bb % ntiles) * 64;
    const int k0 = (bb / ntiles) * 64;
    isQ = (W == wa) && (n0 < 1024);
    const float sc = isQ ? SCALE_EXP2 : 1.0f;

    __shared__ float t[64][65];
    const int r = tid >> 4, c4 = (tid & 15) * 4;
#pragma unroll
    for (int p = 0; p < 4; ++p) {
        const float4 g = *(const float4*)(W + (size_t)(k0 + p * 16 + r) * N + n0 + c4);
        t[p * 16 + r][c4 + 0] = g.x;
        t[p * 16 + r][c4 + 1] = g.y;
        t[p * 16 + r][c4 + 2] = g.z;
        t[p * 16 + r][c4 + 3] = g.w;
    }
    __syncthreads();
#pragma unroll
    for (int p = 0; p < 4; ++p) {
        const int n = p * 16 + r;
        half4 s = {(_Float16)(t[c4 + 0][n] * sc), (_Float16)(t[c4 + 1][n] * sc),
                   (_Float16)(t[c4 + 2][n] * sc), (_Float16)(t[c4 + 3][n] * sc)};
        *(half4*)(WT + (size_t)(n0 + n) * K + k0 + c4) = s;
    }
}

// ---------------------------------------------------------------------------
// 256x256 multi-phase f16 MFMA GEMM — PROVEN ~75 us for QKV shape.
// ---------------------------------------------------------------------------
#define BK2 64

__global__ __launch_bounds__(512, 2) void gemm256(const half_t* __restrict__ A,
                                                  const half_t* __restrict__ Bt,
                                                  half_t* __restrict__ Cout,
                                                  int M, int N, int K) {
    // buf0: A [0,16384), B [16384,32768); buf1: A [32768,49152), B [49152,65536)
    __shared__ __align__(16) half_t SM[65536];   // 128 KiB

    const int tid  = threadIdx.x;
    const int lane = tid & 63;
    const int wid  = tid >> 6;
    const int l16  = lane & 15;
    const int quad = lane >> 4;

    // bijective XCD swizzle (gridDim.x % 8 == 0)
    const int nwg = gridDim.x;
    const int cpx = nwg >> 3;
    const int bid = (blockIdx.x & 7) * cpx + (blockIdx.x >> 3);
    const int nbx = N >> 8;
    const int bx = bid % nbx;
    const int by = bid / nbx;
    const size_t m0 = (size_t)by << 8;
    const size_t n0 = (size_t)bx << 8;

    const int warpM = (wid >> 2) * 128;   // wave's M half
    const int wn    = (wid & 3) * 64;     // wave's 64-col N slice
    const int NTk   = K >> 6;

    // staging: thread t covers row (tid>>3), swizzled chunk (tid&7)^((tid>>3)&7)
    const int srow = tid >> 3;
    const int scsw = (tid & 7) ^ (srow & 7);
    const half_t* gAs = A  + (m0 + srow) * (size_t)K + scsw * 8;
    const half_t* gBs = Bt + (n0 + srow) * (size_t)K + scsw * 8;

    f32x4 acc[8][4];
#pragma unroll
    for (int i = 0; i < 8; ++i)
#pragma unroll
        for (int j = 0; j < 4; ++j) acc[i][j] = (f32x4){0.f, 0.f, 0.f, 0.f};

    // swizzled fragment loads (r&7 == l16&7 since all row bases are %8==0)
    auto ldA = [&](const half_t* Ab, int mt, int kk) -> half8 {
        const int r = warpM + mt * 16 + l16;
        const int c = (kk * 4 + quad) ^ (l16 & 7);
        return *(const half8*)(Ab + r * 64 + c * 8);
    };
    auto ldB = [&](const half_t* Bb, int nt, int kk) -> half8 {
        const int r = wn + nt * 16 + l16;
        const int c = (kk * 4 + quad) ^ (l16 & 7);
        return *(const half8*)(Bb + r * 64 + c * 8);
    };

    // ---- prologue: tile0 (A+B)->buf0, tile1 B->buf1; vmcnt(4) keeps tile1-B in flight
#pragma unroll
    for (int s = 0; s < 4; ++s)
        stage16(gAs + (size_t)(s * 64) * K, SM + s * 4096 + wid * 512);
#pragma unroll
    for (int s = 0; s < 4; ++s)
        stage16(gBs + (size_t)(s * 64) * K, SM + 16384 + s * 4096 + wid * 512);
    if (NTk > 1) {
#pragma unroll
        for (int s = 0; s < 4; ++s)
            stage16(gBs + (size_t)(s * 64) * K + BK2, SM + 49152 + s * 4096 + wid * 512);
        asm volatile("s_waitcnt vmcnt(4)" ::: "memory");
    } else {
        asm volatile("s_waitcnt vmcnt(0)" ::: "memory");
    }
    __builtin_amdgcn_s_barrier();
    __builtin_amdgcn_sched_barrier(0);

    auto tile_body = [&](int t, half_t* Ac, half_t* Bc, half_t* An) {
        const int kA = (t + 1) * BK2;
        const int kB = (t + 2) * BK2;
        const bool doA = (t + 1) < NTk;
        const bool doB = (t + 2) < NTk;

        half8 fb[4][2];

        // ---- phase 0: stage A-half0(t+1); read B-frags + A quad0; MFMA q0
        if (doA) {
            stage16(gAs + (size_t)(0 * 64) * K + kA, An + 0 * 4096 + wid * 512);
            stage16(gAs + (size_t)(1 * 64) * K + kA, An + 1 * 4096 + wid * 512);
        }
#pragma unroll
        for (int nt = 0; nt < 4; ++nt) {
            fb[nt][0] = ldB(Bc, nt, 0);
            fb[nt][1] = ldB(Bc, nt, 1);
        }
        {
            half8 a00 = ldA(Ac, 0, 0), a01 = ldA(Ac, 0, 1);
            half8 a10 = ldA(Ac, 1, 0), a11 = ldA(Ac, 1, 1);
            __builtin_amdgcn_s_barrier();
            __builtin_amdgcn_s_setprio(1);
#pragma unroll
            for (int nt = 0; nt < 4; ++nt) {
                acc[0][nt] = __builtin_amdgcn_mfma_f32_16x16x32_f16(a00, fb[nt][0], acc[0][nt], 0, 0, 0);
                acc[0][nt] = __builtin_amdgcn_mfma_f32_16x16x32_f16(a01, fb[nt][1], acc[0][nt], 0, 0, 0);
                acc[1][nt] = __builtin_amdgcn_mfma_f32_16x16x32_f16(a10, fb[nt][0], acc[1][nt], 0, 0, 0);
                acc[1][nt] = __builtin_amdgcn_mfma_f32_16x16x32_f16(a11, fb[nt][1], acc[1][nt], 0, 0, 0);
            }
            __builtin_amdgcn_s_setprio(0);
        }
        // ---- phase 1: stage A-half1(t+1); A quad1; MFMA q1
        if (doA) {
            stage16(gAs + (size_t)(2 * 64) * K + kA, An + 2 * 4096 + wid * 512);
            stage16(gAs + (size_t)(3 * 64) * K + kA, An + 3 * 4096 + wid * 512);
        }
        {
            half8 a00 = ldA(Ac, 2, 0), a01 = ldA(Ac, 2, 1);
            half8 a10 = ldA(Ac, 3, 0), a11 = ldA(Ac, 3, 1);
            __builtin_amdgcn_s_barrier();
            __builtin_amdgcn_s_setprio(1);
#pragma unroll
            for (int nt = 0; nt < 4; ++nt) {
                acc[2][nt] = __builtin_amdgcn_mfma_f32_16x16x32_f16(a00, fb[nt][0], acc[2][nt], 0, 0, 0);
                acc[2][nt] = __builtin_amdgcn_mfma_f32_16x16x32_f16(a01, fb[nt][1], acc[2][nt], 0, 0, 0);
                acc[3][nt] = __builtin_amdgcn_mfma_f32_16x16x32_f16(a10, fb[nt][0], acc[3][nt], 0, 0, 0);
                acc[3][nt] = __builtin_amdgcn_mfma_f32_16x16x32_f16(a11, fb[nt][1], acc[3][nt], 0, 0, 0);
            }
            __builtin_amdgcn_s_setprio(0);
        }
        // ---- phase 2: stage B-half0(t+2) into Bc; MFMA q2
        if (doB) {
            stage16(gBs + (size_t)(0 * 64) * K + kB, Bc + 0 * 4096 + wid * 512);
            stage16(gBs + (size_t)(1 * 64) * K + kB, Bc + 1 * 4096 + wid * 512);
        }
        {
            half8 a00 = ldA(Ac, 4, 0), a01 = ldA(Ac, 4, 1);
            half8 a10 = ldA(Ac, 5, 0), a11 = ldA(Ac, 5, 1);
            __builtin_amdgcn_s_barrier();
            __builtin_amdgcn_s_setprio(1);
#pragma unroll
            for (int nt = 0; nt < 4; ++nt) {
                acc[4][nt] = __builtin_amdgcn_mfma_f32_16x16x32_f16(a00, fb[nt][0], acc[4][nt], 0, 0, 0);
                acc[4][nt] = __builtin_amdgcn_mfma_f32_16x16x32_f16(a01, fb[nt][1], acc[4][nt], 0, 0, 0);
                acc[5][nt] = __builtin_amdgcn_mfma_f32_16x16x32_f16(a10, fb[nt][0], acc[5][nt], 0, 0, 0);
                acc[5][nt] = __builtin_amdgcn_mfma_f32_16x16x32_f16(a11, fb[nt][1], acc[5][nt], 0, 0, 0);
            }
            __builtin_amdgcn_s_setprio(0);
        }
        // ---- phase 3: stage B-half1(t+2); MFMA q3
        if (doB) {
            stage16(gBs + (size_t)(2 * 64) * K + kB, Bc + 2 * 4096 + wid * 512);
            stage16(gBs + (size_t)(3 * 64) * K + kB, Bc + 3 * 4096 + wid * 512);
        }
        {
            half8 a00 = ldA(Ac, 6, 0), a01 = ldA(Ac, 6, 1);
            half8 a10 = ldA(Ac, 7, 0), a11 = ldA(Ac, 7, 1);
            __builtin_amdgcn_s_barrier();
            __builtin_amdgcn_s_setprio(1);
#pragma unroll
            for (int nt = 0; nt < 4; ++nt) {
                acc[6][nt] = __builtin_amdgcn_mfma_f32_16x16x32_f16(a00, fb[nt][0], acc[6][nt], 0, 0, 0);
                acc[6][nt] = __builtin_amdgcn_mfma_f32_16x16x32_f16(a01, fb[nt][1], acc[6][nt], 0, 0, 0);
                acc[7][nt] = __builtin_amdgcn_mfma_f32_16x16x32_f16(a10, fb[nt][0], acc[7][nt], 0, 0, 0);
                acc[7][nt] = __builtin_amdgcn_mfma_f32_16x16x32_f16(a11, fb[nt][1], acc[7][nt], 0, 0, 0);
            }
            __builtin_amdgcn_s_setprio(0);
        }
        // ---- tile end: counted vmcnt (retire A(t+1)+older; keep B(t+2) in flight)
        if (doB) {
            asm volatile("s_waitcnt vmcnt(4)" ::: "memory");
        } else if (doA) {
            asm volatile("s_waitcnt vmcnt(0)" ::: "memory");
        }
        __builtin_amdgcn_s_barrier();
        __builtin_amdgcn_sched_barrier(0);
    };

    for (int tt = 0; tt < NTk; tt += 2) {
        tile_body(tt, SM, SM + 16384, SM + 32768);
        if (tt + 1 < NTk)
            tile_body(tt + 1, SM + 32768, SM + 49152, SM);
    }

    // ---- epilogue: coalesced f16 stores via per-wave LDS transpose bounce ----
    __syncthreads();
    float* cw = (float*)SM + wid * 1024;   // 4 KB/wave scratch
    const int rrow = lane >> 2;            // 0..15
    const int cseg = (lane & 3) * 16;      // 0,16,32,48
#pragma unroll
    for (int mt = 0; mt < 8; ++mt) {
#pragma unroll
        for (int nt = 0; nt < 4; ++nt)
            *(f32x4*)&cw[(nt * 16 + l16) * 16 + quad * 4] = acc[mt][nt];
        // wave-internal LDS dep: DS ops are processed in order per wave
        half_t tmp[16];
#pragma unroll
        for (int jj = 0; jj < 16; ++jj)
            tmp[jj] = (half_t)cw[(cseg + jj) * 16 + rrow];
        half_t* dst = Cout + (m0 + warpM + mt * 16 + rrow) * (size_t)N + n0 + wn + cseg;
        *(half8*)(dst)     = *(const half8*)(tmp);
        *(half8*)(dst + 8) = *(const half8*)(tmp + 8);
    }
}

// ---------------------------------------------------------------------------
// 128x256 multi-phase f16 MFMA GEMM (for proj: 256 blocks = 1 full round).
// f32 out. Proven structure, unchanged.
// ---------------------------------------------------------------------------
__global__ __launch_bounds__(512, 2) void gemm128f(const half_t* __restrict__ A,
                                                   const half_t* __restrict__ Bt,
                                                   float* __restrict__ Cout,
                                                   int M, int N, int K) {
    // halfs: A0 [0,8192) B0 [8192,24576) A1 [24576,32768) B1 [32768,49152)
    __shared__ __align__(16) half_t SM[49152];   // 96 KiB

    const int tid  = threadIdx.x;
    const int lane = tid & 63;
    const int wid  = tid >> 6;
    const int l16  = lane & 15;
    const int quad = lane >> 4;

    // bijective XCD swizzle (gridDim.x % 8 == 0)
    const int nwg = gridDim.x;
    const int cpx = nwg >> 3;
    const int bid = (blockIdx.x & 7) * cpx + (blockIdx.x >> 3);
    const int nbx = N >> 8;                 // 256-col tiles
    const int bx = bid % nbx;
    const int by = bid / nbx;
    const size_t m0 = (size_t)by << 7;      // 128-row tiles
    const size_t n0 = (size_t)bx << 8;

    const int warpM = (wid >> 2) * 64;      // wave's M half (64 rows)
    const int wn    = (wid & 3) * 64;       // wave's 64-col N slice
    const int NTk   = K >> 6;

    const int srow = tid >> 3;
    const int scsw = (tid & 7) ^ (srow & 7);
    const half_t* gAs = A  + (m0 + srow) * (size_t)K + scsw * 8;
    const half_t* gBs = Bt + (n0 + srow) * (size_t)K + scsw * 8;

    half_t* const A0 = SM;
    half_t* const B0 = SM + 8192;
    half_t* const A1 = SM + 24576;
    half_t* const B1 = SM + 32768;

    f32x4 acc[4][4];
#pragma unroll
    for (int i = 0; i < 4; ++i)
#pragma unroll
        for (int j = 0; j < 4; ++j) acc[i][j] = (f32x4){0.f, 0.f, 0.f, 0.f};

    auto ldA = [&](const half_t* Ab, int mt, int kk) -> half8 {
        const int r = warpM + mt * 16 + l16;
        const int c = (kk * 4 + quad) ^ (l16 & 7);
        return *(const half8*)(Ab + r * 64 + c * 8);
    };
    auto ldB = [&](const half_t* Bb, int nt, int kk) -> half8 {
        const int r = wn + nt * 16 + l16;
        const int c = (kk * 4 + quad) ^ (l16 & 7);
        return *(const half8*)(Bb + r * 64 + c * 8);
    };

    // ---- prologue: tile0 A(2)+B(4)->buf0, tile1 B(4)->buf1; vmcnt(4)
#pragma unroll
    for (int s = 0; s < 2; ++s)
        stage16(gAs + (size_t)(s * 64) * K, A0 + s * 4096 + wid * 512);
#pragma unroll
    for (int s = 0; s < 4; ++s)
        stage16(gBs + (size_t)(s * 64) * K, B0 + s * 4096 + wid * 512);
    if (NTk > 1) {
#pragma unroll
        for (int s = 0; s < 4; ++s)
            stage16(gBs + (size_t)(s * 64) * K + BK2, B1 + s * 4096 + wid * 512);
        asm volatile("s_waitcnt vmcnt(4)" ::: "memory");
    } else {
        asm volatile("s_waitcnt vmcnt(0)" ::: "memory");
    }
    __builtin_amdgcn_s_barrier();
    __builtin_amdgcn_sched_barrier(0);

    auto tile_body = [&](int t, half_t* Ac, half_t* Bc, half_t* An) {
        const int kA = (t + 1) * BK2;
        const int kB = (t + 2) * BK2;
        const bool doA = (t + 1) < NTk;
        const bool doB = (t + 2) < NTk;

        half8 fb[4][2];

        // ---- phase A: stage A(t+1) [2]; read ALL B-frags + A mt0/mt1; MFMA
        if (doA) {
            stage16(gAs + (size_t)(0 * 64) * K + kA, An + 0 * 4096 + wid * 512);
            stage16(gAs + (size_t)(1 * 64) * K + kA, An + 1 * 4096 + wid * 512);
        }
#pragma unroll
        for (int nt = 0; nt < 4; ++nt) {
            fb[nt][0] = ldB(Bc, nt, 0);
            fb[nt][1] = ldB(Bc, nt, 1);
        }
        {
            half8 a00 = ldA(Ac, 0, 0), a01 = ldA(Ac, 0, 1);
            half8 a10 = ldA(Ac, 1, 0), a11 = ldA(Ac, 1, 1);
            __builtin_amdgcn_s_barrier();
            __builtin_amdgcn_s_setprio(1);
#pragma unroll
            for (int nt = 0; nt < 4; ++nt) {
                acc[0][nt] = __builtin_amdgcn_mfma_f32_16x16x32_f16(a00, fb[nt][0], acc[0][nt], 0, 0, 0);
                acc[0][nt] = __builtin_amdgcn_mfma_f32_16x16x32_f16(a01, fb[nt][1], acc[0][nt], 0, 0, 0);
                acc[1][nt] = __builtin_amdgcn_mfma_f32_16x16x32_f16(a10, fb[nt][0], acc[1][nt], 0, 0, 0);
                acc[1][nt] = __builtin_amdgcn_mfma_f32_16x16x32_f16(a11, fb[nt][1], acc[1][nt], 0, 0, 0);
            }
            __builtin_amdgcn_s_setprio(0);
        }
        // ---- phase B: stage B(t+2) [4] into Bc (fb fully read); A mt2/mt3; MFMA
        if (doB) {
#pragma unroll
            for (int s = 0; s < 4; ++s)
                stage16(gBs + (size_t)(s * 64) * K + kB, Bc + s * 4096 + wid * 512);
        }
        {
            half8 a00 = ldA(Ac, 2, 0), a01 = ldA(Ac, 2, 1);
            half8 a10 = ldA(Ac, 3, 0), a11 = ldA(Ac, 3, 1);
            __builtin_amdgcn_s_barrier();
            __builtin_amdgcn_s_setprio(1);
#pragma unroll
            for (int nt = 0; nt < 4; ++nt) {
                acc[2][nt] = __builtin_amdgcn_mfma_f32_16x16x32_f16(a00, fb[nt][0], acc[2][nt], 0, 0, 0);
                acc[2][nt] = __builtin_amdgcn_mfma_f32_16x16x32_f16(a01, fb[nt][1], acc[2][nt], 0, 0, 0);
                acc[3][nt] = __builtin_amdgcn_mfma_f32_16x16x32_f16(a10, fb[nt][0], acc[3][nt], 0, 0, 0);
                acc[3][nt] = __builtin_amdgcn_mfma_f32_16x16x32_f16(a11, fb[nt][1], acc[3][nt], 0, 0, 0);
            }
            __builtin_amdgcn_s_setprio(0);
        }
        // ---- tile end: counted vmcnt
        if (doB) {
            asm volatile("s_waitcnt vmcnt(4)" ::: "memory");
        } else if (doA) {
            asm volatile("s_waitcnt vmcnt(0)" ::: "memory");
        }
        __builtin_amdgcn_s_barrier();
        __builtin_amdgcn_sched_barrier(0);
    };

    for (int tt = 0; tt < NTk; tt += 2) {
        tile_body(tt, A0, B0, A1);
        if (tt + 1 < NTk)
            tile_body(tt + 1, A1, B1, A0);
    }

    // ---- epilogue: f32 direct coalesced-per-quad stores ----
#pragma unroll
    for (int mt = 0; mt < 4; ++mt)
#pragma unroll
        for (int nt = 0; nt < 4; ++nt)
#pragma unroll
            for (int r = 0; r < 4; ++r) {
                const size_t row = m0 + warpM + mt * 16 + quad * 4 + r;
                const size_t col = n0 + wn + nt * 16 + l16;
                Cout[row * (size_t)N + col] = acc[mt][nt][r];
            }
}

// ---------------------------------------------------------------------------
// MFMA flash attention v7: v5 body, UNPAIRED jobs — one 128-row Q job per
// block, grid 1024 (~4 blocks/CU; was 512 paired = 2/CU, grid-limited
// occupancy 35%). jj = 15 - (L>>6): longest jobs dispatch first so the
// imbalanced lengths pack (longest 32 tiles << per-CU total ~68).
// Body byte-identical to proven v5 otherwise.
// ---------------------------------------------------------------------------
__global__ __launch_bounds__(256, 2) void attn_mfma(const half_t* __restrict__ qkv,
                                                    half_t* __restrict__ y) {
    __shared__ __align__(16) half_t Kl[64 * 64];
    __shared__ __align__(16) half_t Vt[64 * 64];
    __shared__ float Lstat[128];

    const int tid  = threadIdx.x;
    const int wid  = tid >> 6;
    const int lane = tid & 63;
    const int l16  = lane & 15;
    const int quad = lane >> 4;

    const int L = blockIdx.x;
    const int g = L & 63;                 // (b,h) group -> fixed XCD (g % 8)
    const int jj = 15 - (L >> 6);         // job index 15..0, biggest first
    const int h = g & 15;
    const int b = g >> 4;

    const size_t rs = 3 * C_EMB;
    const half_t* qb = qkv + (size_t)b * T_SEQ * rs + h * HS;
    const half_t* kb = qb + C_EMB;
    const half_t* vb = qb + 2 * C_EMB;

    const int srow = tid >> 2;            // 0..63
    const int scol = (tid & 3) * 16;      // 0,16,32,48 (halfs, global)
    const int sc2  = (tid & 3) * 2;       // LDS chunk pair base (16B chunks)
    const int rp   = tid & 31;            // row pair: rows 2rp, 2rp+1
    const int dblk = tid >> 5;            // 0..7 -> d = dblk*8 .. +8

    const int wq = wid * 32;              // wave's 32-q base within 128 tile

    // swizzled addressing: 16B chunk c of row r lives at chunk c^(r&7)
    auto kswz = [&](int row, int chunk) -> half_t* {
        return Kl + row * 64 + ((chunk ^ (row & 7)) << 3);
    };
    auto vswz = [&](int row, int chunk) -> half_t* {
        return Vt + row * 64 + ((chunk ^ (row & 7)) << 3);
    };

    {
        const int q0 = jj * 128;
        const int ntk = 2 * jj + 2;               // k-tiles 0..2jj+1

        // ---- Q direct global -> regs (two 16-row subsets per wave) ----
        half8 aQ[2][2];
#pragma unroll
        for (int qs = 0; qs < 2; ++qs)
#pragma unroll
            for (int s2 = 0; s2 < 2; ++s2)
                aQ[qs][s2] = *(const half8*)(qb +
                    (size_t)(q0 + wq + qs * 16 + l16) * rs + s2 * 32 + quad * 8);

        // ---- prefetch k-tile 0 K/V into regs ----
        const half_t* kptr = kb + (size_t)srow * rs + scol;
        const half_t* vptr = vb + (size_t)(2 * rp) * rs + dblk * 8;
        half8 kp0, kp1;
        uint4 vpa, vpc;
        kp0 = *(const half8*)(kptr);
        kp1 = *(const half8*)(kptr + 8);
        vpa = *(const uint4*)(vptr);
        vpc = *(const uint4*)(vptr + rs);

        f32x4 O[2][4];
#pragma unroll
        for (int qs = 0; qs < 2; ++qs)
#pragma unroll
            for (int dt = 0; dt < 4; ++dt) O[qs][dt] = (f32x4){0.f, 0.f, 0.f, 0.f};
        float lw[2] = {0.f, 0.f};

        for (int kt = 0; kt < ntk; ++kt) {
            __syncthreads();   // prior tile frag reads done

            // ---- write prefetched K: Kl[kcol][d], swizzled ----
            *(half8*)kswz(srow, sc2)     = kp0;
            *(half8*)kswz(srow, sc2 + 1) = kp1;
            // ---- write prefetched V^T: Vt[d][kcol], paired-row b32 packing ----
            {
                const uint32_t a0[4] = {vpa.x, vpa.y, vpa.z, vpa.w};
                const uint32_t c0[4] = {vpc.x, vpc.y, vpc.z, vpc.w};
#pragma unroll
                for (int u = 0; u < 4; ++u) {
                    const int d0 = dblk * 8 + 2 * u;
                    const uint32_t w0 = (a0[u] & 0xffffu) | (c0[u] << 16);
                    const uint32_t w1 = (a0[u] >> 16) | (c0[u] & 0xffff0000u);
                    *(uint32_t*)((unsigned short*)vswz(d0,     rp >> 2) + (rp & 3) * 2) = w0;
                    *(uint32_t*)((unsigned short*)vswz(d0 + 1, rp >> 2) + (rp & 3) * 2) = w1;
                }
            }
            __syncthreads();

            // ---- T14: issue next tile's loads (increment-only addressing) ----
            if (kt + 1 < ntk) {
                kptr += 64 * rs;
                vptr += 64 * rs;
                kp0 = *(const half8*)(kptr);
                kp1 = *(const half8*)(kptr + 8);
                vpa = *(const uint4*)(vptr);
                vpc = *(const uint4*)(vptr + rs);
            }

            const bool dmask = (kt >= ntk - 2);   // last two tiles may need mask

            // ---- fused: S^T MFMA -> exp2 -> P frag -> O += P@V, two q-subsets ----
#pragma unroll
            for (int mt = 0; mt < 4; ++mt) {
                const half8 aK0 = *(const half8*)kswz(mt * 16 + l16, quad);
                const half8 aK1 = *(const half8*)kswz(mt * 16 + l16, 4 + quad);
                half4 bV[4];
#pragma unroll
                for (int dt = 0; dt < 4; ++dt)
                    bV[dt] = *(const half4*)(vswz(dt * 16 + l16, 2 * mt + (quad >> 1)) +
                                             (quad & 1) * 4);
                const int kbase = kt * 64 + mt * 16 + quad * 4;   // global k of p[0]
#pragma unroll
                for (int qs = 0; qs < 2; ++qs) {
                    f32x4 sa = (f32x4){0.f, 0.f, 0.f, 0.f};
                    sa = __builtin_amdgcn_mfma_f32_16x16x32_f16(aK0, aQ[qs][0], sa, 0, 0, 0);
                    sa = __builtin_amdgcn_mfma_f32_16x16x32_f16(aK1, aQ[qs][1], sa, 0, 0, 0);

                    float p[4];
#pragma unroll
                    for (int r = 0; r < 4; ++r)
                        p[r] = __builtin_amdgcn_exp2f(sa[r]);   // scale pre-folded into Q
                    if (dmask) {
                        const int qg = q0 + wq + qs * 16 + l16;   // global q row
#pragma unroll
                        for (int r = 0; r < 4; ++r)
                            if (kbase + r > qg) p[r] = 0.f;
                    }
                    lw[qs] += (p[0] + p[1]) + (p[2] + p[3]);

                    const half4 pa = {(_Float16)p[0], (_Float16)p[1],
                                      (_Float16)p[2], (_Float16)p[3]};
#pragma unroll
                    for (int dt = 0; dt < 4; ++dt)
                        O[qs][dt] = mfma_k16(pa, bV[dt], O[qs][dt]);
                }
            }
        }

        // ---- epilogue: l-reduce, normalize, coalesced store via LDS (2 passes) ----
#pragma unroll
        for (int qs = 0; qs < 2; ++qs) {
            lw[qs] += __shfl_xor(lw[qs], 16);
            lw[qs] += __shfl_xor(lw[qs], 32);
            if (quad == 0) Lstat[wq + qs * 16 + l16] = lw[qs];
        }
        __syncthreads();   // all waves done reading Vt/Kl; Lstat visible

        // pass A: q-rows 0..63 (waves 0,1)
        if (wid < 2) {
#pragma unroll
            for (int qs = 0; qs < 2; ++qs)
#pragma unroll
                for (int r = 0; r < 4; ++r) {
                    const int rowl = wq + qs * 16 + quad * 4 + r;   // 0..63
                    const float inv = 1.f / Lstat[rowl];
#pragma unroll
                    for (int dt = 0; dt < 4; ++dt)
                        *(vswz(rowl, 2 * dt + (l16 >> 3)) + (l16 & 7)) =
                            (half_t)(O[qs][dt][r] * inv);
                }
        }
        __syncthreads();
        {
            half_t* dst = y + ((size_t)b * T_SEQ + q0 + srow) * C_EMB + h * HS + scol;
            *(half8*)(dst)     = *(const half8*)vswz(srow, sc2);
            *(half8*)(dst + 8) = *(const half8*)vswz(srow, sc2 + 1);
        }
        __syncthreads();

        // pass B: q-rows 64..127 (waves 2,3)
        if (wid >= 2) {
#pragma unroll
            for (int qs = 0; qs < 2; ++qs)
#pragma unroll
                for (int r = 0; r < 4; ++r) {
                    const int rowg = wq + qs * 16 + quad * 4 + r;   // 64..127
                    const float inv = 1.f / Lstat[rowg];
#pragma unroll
                    for (int dt = 0; dt < 4; ++dt)
                        *(vswz(rowg - 64, 2 * dt + (l16 >> 3)) + (l16 & 7)) =
                            (half_t)(O[qs][dt][r] * inv);
                }
        }
        __syncthreads();
        {
            half_t* dst = y + ((size_t)b * T_SEQ + q0 + 64 + srow) * C_EMB + h * HS + scol;
            *(half8*)(dst)     = *(const half8*)vswz(srow, sc2);
            *(half8*)(dst + 8) = *(const half8*)vswz(srow, sc2 + 1);
        }
    }
}

// ---------------------------------------------------------------------------
extern "C" void kernel_launch(void* const* d_in, const int* in_sizes, int n_in,
                              void* d_out, int out_size, void* d_ws, size_t ws_size,
                              hipStream_t stream) {
    const float* x      = (const float*)d_in[0];   // [8192,1024]
    const float* w_attn = (const float*)d_in[1];   // [1024,3072]
    const float* w_proj = (const float*)d_in[2];   // [1024,1024]
    float* out = (float*)d_out;

    half_t* xh   = (half_t*)d_ws;                        // 16 MB
    half_t* waT  = xh   + (size_t)8192 * 1024;           //  6 MB [3072][1024]
    half_t* wpT  = waT  + (size_t)3072 * 1024;           //  2 MB [1024][1024]
    half_t* qkvh = wpT  + (size_t)1024 * 1024;           // 48 MB [8192][3072]
    half_t* yh   = qkvh + (size_t)8192 * 3072;           // 16 MB [8192][1024]

    // merged prep: x convert + both weight transposes (Q-cols pre-scaled)
    prep_kernel<<<5120, 256, 0, stream>>>(x, xh, w_attn, waT, w_proj, wpT);

    // qkv = x @ w_attn   (256x256 template — proven)
    gemm256<<<dim3(384), 512, 0, stream>>>(xh, waT, qkvh, 8192, 3072, 1024);

    // attention v7: 1024 unpaired 128-q blocks, biggest jobs first
    attn_mfma<<<dim3(1024), 256, 0, stream>>>(qkvh, yh);

    // out = y @ w_proj   (128x256 template, 256 blocks = 1 full round, f32 out)
    gemm128f<<<dim3(256), 512, 0, stream>>>(yh, wpT, out, 8192, 1024, 1024);
}